// Round 4
// baseline (434.398 us; speedup 1.0000x reference)
//
#include <hip/hip_runtime.h>
#include <math.h>

#define ATOM 64

// ===========================================================================
// Shared device helpers
// ===========================================================================

// D[k][q] = sum_l B[l][k] * B[l][q], with B[l][q] = Rsum[l]*be2[q] + sum_e Bh[l][e]*We2[e][q]
// e2 column layout: e2[q] = { be2[q], We2[0][q], ..., We2[9][q], pad }
__device__ __forceinline__ void make_D(const float (&Bh)[4][10], const float (&Rsum)[4],
                                       const float (*e2)[12], float (&D)[20])
{
    float Bk[2][4];
#pragma unroll
    for (int k=0;k<2;++k) {
        const float4 c0 = *(const float4*)&e2[k][0];
        const float4 c1 = *(const float4*)&e2[k][4];
        const float4 c2 = *(const float4*)&e2[k][8];
#pragma unroll
        for (int l=0;l<4;++l) {
            Bk[k][l] = Rsum[l]*c0.x + Bh[l][0]*c0.y + Bh[l][1]*c0.z + Bh[l][2]*c0.w
                     + Bh[l][3]*c1.x + Bh[l][4]*c1.y + Bh[l][5]*c1.z + Bh[l][6]*c1.w
                     + Bh[l][7]*c2.x + Bh[l][8]*c2.y + Bh[l][9]*c2.z;
        }
    }
#pragma unroll
    for (int q=0;q<10;++q) {
        const float4 c0 = *(const float4*)&e2[q][0];
        const float4 c1 = *(const float4*)&e2[q][4];
        const float4 c2 = *(const float4*)&e2[q][8];
        float Bq[4];
#pragma unroll
        for (int l=0;l<4;++l) {
            Bq[l] = Rsum[l]*c0.x + Bh[l][0]*c0.y + Bh[l][1]*c0.z + Bh[l][2]*c0.w
                  + Bh[l][3]*c1.x + Bh[l][4]*c1.y + Bh[l][5]*c1.z + Bh[l][6]*c1.w
                  + Bh[l][7]*c2.x + Bh[l][8]*c2.y + Bh[l][9]*c2.z;
        }
        D[q]    = Bk[0][0]*Bq[0]+Bk[0][1]*Bq[1]+Bk[0][2]*Bq[2]+Bk[0][3]*Bq[3];
        D[10+q] = Bk[1][0]*Bq[0]+Bk[1][1]*Bq[1]+Bk[1][2]*Bq[2]+Bk[1][3]*Bq[3];
    }
}

// quad-cooperative MLP head (used by fused fallback only)
__device__ __forceinline__ float mlp_head_quad(const float* __restrict__ x,
                                          const float* __restrict__ w1, const float* __restrict__ b1,
                                          const float* __restrict__ w2, const float* __restrict__ b2,
                                          const float* __restrict__ w3, int j)
{
    float h1[8];
    {
        float4 ba = *(const float4*)(b1 + 8*j);
        float4 bb = *(const float4*)(b1 + 8*j + 4);
        h1[0]=ba.x; h1[1]=ba.y; h1[2]=ba.z; h1[3]=ba.w;
        h1[4]=bb.x; h1[5]=bb.y; h1[6]=bb.z; h1[7]=bb.w;
    }
#pragma unroll
    for (int d=0; d<20; ++d) {
        float4 w0 = *(const float4*)(w1 + d*32 + 8*j);
        float4 w4 = *(const float4*)(w1 + d*32 + 8*j + 4);
        float xv = x[d];
        h1[0] += xv*w0.x; h1[1] += xv*w0.y; h1[2] += xv*w0.z; h1[3] += xv*w0.w;
        h1[4] += xv*w4.x; h1[5] += xv*w4.y; h1[6] += xv*w4.z; h1[7] += xv*w4.w;
    }
#pragma unroll
    for (int o=0;o<8;++o) h1[o] = fmaxf(h1[o], 0.f);

    float s = 0.f;
#pragma unroll
    for (int half=0; half<2; ++half) {
        float p[16];
#pragma unroll
        for (int q=0;q<16;++q) p[q] = 0.f;
#pragma unroll
        for (int o=0;o<8;++o) {
            const float* row = w2 + (8*j + o)*32 + 16*half;
            float hv = h1[o];
#pragma unroll
            for (int q=0;q<4;++q) {
                float4 w = *(const float4*)(row + 4*q);
                p[4*q+0] += hv*w.x; p[4*q+1] += hv*w.y;
                p[4*q+2] += hv*w.z; p[4*q+3] += hv*w.w;
            }
        }
#pragma unroll
        for (int q=0;q<16;++q) { p[q] += __shfl_xor(p[q],1); p[q] += __shfl_xor(p[q],2); }
#pragma unroll
        for (int q=0;q<4;++q) {
            float4 bq = *(const float4*)(b2 + 16*half + 4*q);
            float4 wq = *(const float4*)(w3 + 16*half + 4*q);
            s += fmaxf(p[4*q+0]+bq.x, 0.f)*wq.x;
            s += fmaxf(p[4*q+1]+bq.y, 0.f)*wq.y;
            s += fmaxf(p[4*q+2]+bq.z, 0.f)*wq.z;
            s += fmaxf(p[4*q+3]+bq.w, 0.f)*wq.w;
        }
    }
    return s;
}

// full per-thread MLP head: x[20] -> 32 -> 32 -> 1 (bias3 added by caller)
__device__ __forceinline__ float full_head(const float (&x)[20],
                                           const float* __restrict__ w1, const float* __restrict__ b1,
                                           const float* __restrict__ w2, const float* __restrict__ b2,
                                           const float* __restrict__ w3)
{
    float h1[32];
#pragma unroll
    for (int q=0;q<8;++q) {
        float4 b = *(const float4*)(b1 + 4*q);
        h1[4*q+0]=b.x; h1[4*q+1]=b.y; h1[4*q+2]=b.z; h1[4*q+3]=b.w;
    }
#pragma unroll
    for (int d=0; d<20; ++d) {
        const float xv = x[d];
        const float* row = w1 + d*32;
#pragma unroll
        for (int q=0;q<8;++q) {
            float4 w = *(const float4*)(row + 4*q);
            h1[4*q+0] += xv*w.x; h1[4*q+1] += xv*w.y;
            h1[4*q+2] += xv*w.z; h1[4*q+3] += xv*w.w;
        }
    }
    float p[32];
#pragma unroll
    for (int q=0;q<8;++q) {
        float4 b = *(const float4*)(b2 + 4*q);
        p[4*q+0]=b.x; p[4*q+1]=b.y; p[4*q+2]=b.z; p[4*q+3]=b.w;
    }
#pragma unroll
    for (int o=0;o<32;++o) {
        const float hv = fmaxf(h1[o], 0.f);
        const float* row = w2 + o*32;
#pragma unroll
        for (int q=0;q<8;++q) {
            float4 w = *(const float4*)(row + 4*q);
            p[4*q+0] += hv*w.x; p[4*q+1] += hv*w.y;
            p[4*q+2] += hv*w.z; p[4*q+3] += hv*w.w;
        }
    }
    float s = 0.f;
#pragma unroll
    for (int q=0;q<8;++q) {
        float4 wq = *(const float4*)(w3 + 4*q);
        s += fmaxf(p[4*q+0], 0.f)*wq.x;
        s += fmaxf(p[4*q+1], 0.f)*wq.y;
        s += fmaxf(p[4*q+2], 0.f)*wq.z;
        s += fmaxf(p[4*q+3], 0.f)*wq.w;
    }
    return s;
}

// ===========================================================================
// Kernel A: descriptor only. 4 lanes/action, 64 actions/block.
// Writes Df/Dv per action into Dws, transposed layout Dws[c*n + act], c=0..39.
// ===========================================================================
__global__ void k_desc(
    const float* __restrict__ Smat, const float* __restrict__ Rraw, const float* __restrict__ Mspec,
    const float* __restrict__ We1, const float* __restrict__ be1,
    const float* __restrict__ We2, const float* __restrict__ be2,
    float* __restrict__ Dws, int n)
{
    __shared__ __align__(16) float4 s_e1[10];     // {b_e1[e], We1[0][e], We1[1][e], We1[2][e]}
    __shared__ __align__(16) float  s_e2[10][12]; // col q: {b_e2[q], We2[0..9][q], pad}
    __shared__ __align__(16) float  s_a0[64][16]; // per-action atom-0 {h0[10], R0[4]}

    const int tid = threadIdx.x;
    if (tid<10){
        s_e1[tid] = make_float4(be1[tid], We1[tid], We1[10+tid], We1[20+tid]);
        s_e2[tid][0] = be2[tid];
        for (int e=0;e<10;++e) s_e2[tid][1+e] = We2[e*10+tid];
        s_e2[tid][11] = 0.f;
    }
    __syncthreads();

    const int j    = tid & 3;
    const int grp  = tid >> 2;
    const int act  = blockIdx.x*64 + grp;
    const bool active = act < n;
    const int actc = active ? act : (n-1);

    const float*  sp = Smat + (size_t)actc*ATOM;
    const float4* rp = (const float4*)Rraw  + (size_t)actc*ATOM;
    const float4* mp = (const float4*)Mspec + (size_t)actc*48;

    float Bh[4][10];
    float Rsum[4] = {0.f,0.f,0.f,0.f};
#pragma unroll
    for (int l=0;l<4;++l)
#pragma unroll
        for (int e=0;e<10;++e) Bh[l][e]=0.f;

#pragma unroll 1
    for (int c=0;c<4;++c) {
        const int a0 = 16*j + 4*c;
        const float4 s4 = *(const float4*)(sp + a0);
        const float4 rv0 = rp[a0+0];
        const float4 rv1 = rp[a0+1];
        const float4 rv2 = rp[a0+2];
        const float4 rv3 = rp[a0+3];
        const float4 mA = mp[12*j+3*c+0];
        const float4 mB = mp[12*j+3*c+1];
        const float4 mC = mp[12*j+3*c+2];

        const float  sv[4]  = {s4.x,s4.y,s4.z,s4.w};
        const float4 rv[4]  = {rv0,rv1,rv2,rv3};
        const float  mk[12] = {mA.x,mA.y,mA.z,mA.w,mB.x,mB.y,mB.z,mB.w,mC.x,mC.y,mC.z,mC.w};

#pragma unroll
        for (int u=0;u<4;++u) {
            const float s   = sv[u];
            const float Rl0 = s*rv[u].x, Rl1 = s*rv[u].y, Rl2 = s*rv[u].z, Rl3 = s*rv[u].w;
            const float sg0 = s*mk[3*u+0], sg1 = s*mk[3*u+1], sg2 = s*mk[3*u+2];
            float h[10];
#pragma unroll
            for (int e=0;e<10;++e) {
                const float4 w = s_e1[e];
                h[e] = fmaxf(0.f, w.x + sg0*w.y + sg1*w.z + sg2*w.w);
            }
            Rsum[0]+=Rl0; Rsum[1]+=Rl1; Rsum[2]+=Rl2; Rsum[3]+=Rl3;
#pragma unroll
            for (int e=0;e<10;++e) {
                const float he = h[e];
                Bh[0][e]+=Rl0*he; Bh[1][e]+=Rl1*he; Bh[2][e]+=Rl2*he; Bh[3][e]+=Rl3*he;
            }
            if (c==0 && u==0 && j==0) {
#pragma unroll
                for (int e=0;e<10;++e) s_a0[grp][e]=h[e];
                s_a0[grp][10]=Rl0; s_a0[grp][11]=Rl1; s_a0[grp][12]=Rl2; s_a0[grp][13]=Rl3;
            }
        }
    }

#pragma unroll
    for (int l=0;l<4;++l) {
        float v=Rsum[l]; v+=__shfl_xor(v,1); v+=__shfl_xor(v,2); Rsum[l]=v;
#pragma unroll
        for (int e=0;e<10;++e) {
            float w=Bh[l][e]; w+=__shfl_xor(w,1); w+=__shfl_xor(w,2); Bh[l][e]=w;
        }
    }

    float Df[20];
    make_D(Bh, Rsum, s_e2, Df);

    {
        const float* a0p = &s_a0[grp][0];
#pragma unroll
        for (int l=0;l<4;++l) {
            const float r0 = a0p[10+l];
            Rsum[l] -= r0;
#pragma unroll
            for (int e=0;e<10;++e) Bh[l][e] -= r0*a0p[e];
        }
    }
    float Dv[20];
    make_D(Bh, Rsum, s_e2, Dv);

    if (active) {
        const size_t N = (size_t)n;
        if (j==0) {
#pragma unroll
            for (int d=0;d<10;++d) Dws[(size_t)d*N + act] = Df[d];
        } else if (j==1) {
#pragma unroll
            for (int d=0;d<10;++d) Dws[(size_t)(10+d)*N + act] = Df[10+d];
        } else if (j==2) {
#pragma unroll
            for (int d=0;d<10;++d) Dws[(size_t)(20+d)*N + act] = Dv[d];
        } else {
#pragma unroll
            for (int d=0;d<10;++d) Dws[(size_t)(30+d)*N + act] = Dv[10+d];
        }
    }
}

// ===========================================================================
// Kernel B: 1 thread = 1 action, both heads; weights in LDS (uniform broadcast).
// Emits logits + per-block softmax/value partials (256 actions/block).
// ===========================================================================
__global__ void k_mlp(
    const float* __restrict__ Dws,
    const float* __restrict__ Wf1, const float* __restrict__ bf1,
    const float* __restrict__ Wf2, const float* __restrict__ bf2,
    const float* __restrict__ Wf3, const float* __restrict__ bf3,
    const float* __restrict__ Wv1, const float* __restrict__ bv1,
    const float* __restrict__ Wv2, const float* __restrict__ bv2,
    const float* __restrict__ Wv3, const float* __restrict__ bv3,
    float* __restrict__ logits, float* __restrict__ pmax,
    float* __restrict__ psum, float* __restrict__ pval, int n)
{
    __shared__ __align__(16) float s_f1[640], s_v1[640];
    __shared__ __align__(16) float s_f2[1024], s_v2[1024];
    __shared__ __align__(16) float s_b1[32], s_b2[32], s_f3[32];
    __shared__ __align__(16) float s_bv1[32], s_bv2[32], s_v3[32];
    __shared__ float red_l[256], red_v[256];

    const int tid = threadIdx.x;
    for (int i=tid;i<640;i+=256){ s_f1[i]=Wf1[i]; s_v1[i]=Wv1[i]; }
    for (int i=tid;i<1024;i+=256){ s_f2[i]=Wf2[i]; s_v2[i]=Wv2[i]; }
    if (tid<32){ s_b1[tid]=bf1[tid]; s_b2[tid]=bf2[tid]; s_f3[tid]=Wf3[tid];
                 s_bv1[tid]=bv1[tid]; s_bv2[tid]=bv2[tid]; s_v3[tid]=Wv3[tid]; }
    __syncthreads();

    const int i = blockIdx.x*256 + tid;
    const bool active = i < n;
    const int ic = active ? i : (n-1);
    const size_t N = (size_t)n;

    float x[20];
#pragma unroll
    for (int c=0;c<20;++c) x[c] = Dws[(size_t)c*N + ic];
    const float logit = full_head(x, s_f1, s_b1, s_f2, s_b2, s_f3) + bf3[0];

#pragma unroll
    for (int c=0;c<20;++c) x[c] = Dws[(size_t)(20+c)*N + ic];
    const float vout  = full_head(x, s_v1, s_bv1, s_v2, s_bv2, s_v3) + bv3[0];

    if (active) logits[i] = logit;
    red_l[tid] = active ? logit : -INFINITY;
    red_v[tid] = active ? vout  : 0.f;
    __syncthreads();

    if (tid < 64) {
        float m = red_l[tid];
#pragma unroll
        for (int k=1;k<4;++k) m = fmaxf(m, red_l[tid+64*k]);
#pragma unroll
        for (int k=1;k<64;k<<=1) m = fmaxf(m, __shfl_xor(m,k));
        float ssum = 0.f, vsum = 0.f;
#pragma unroll
        for (int k=0;k<4;++k) {
            ssum += expf(red_l[tid+64*k] - m);   // -inf -> 0
            vsum += red_v[tid+64*k];
        }
#pragma unroll
        for (int k=1;k<64;k<<=1){ ssum += __shfl_xor(ssum,k); vsum += __shfl_xor(vsum,k); }
        if (tid==0){ pmax[blockIdx.x]=m; psum[blockIdx.x]=ssum; pval[blockIdx.x]=vsum; }
    }
}

// ===========================================================================
// Fused fallback (R3 structure, default register allocation)
// ===========================================================================
__global__ void k_fused(
    const float* __restrict__ Smat, const float* __restrict__ Rraw, const float* __restrict__ Mspec,
    const float* __restrict__ We1, const float* __restrict__ be1,
    const float* __restrict__ We2, const float* __restrict__ be2,
    const float* __restrict__ Wf1, const float* __restrict__ bf1,
    const float* __restrict__ Wf2, const float* __restrict__ bf2,
    const float* __restrict__ Wf3, const float* __restrict__ bf3,
    const float* __restrict__ Wv1, const float* __restrict__ bv1,
    const float* __restrict__ Wv2, const float* __restrict__ bv2,
    const float* __restrict__ Wv3, const float* __restrict__ bv3,
    float* __restrict__ logits, float* __restrict__ pmax,
    float* __restrict__ psum, float* __restrict__ pval, int n)
{
    __shared__ __align__(16) float4 s_e1[10];
    __shared__ __align__(16) float  s_e2[10][12];
    __shared__ __align__(16) float  s_f1[640], s_v1[640];
    __shared__ __align__(16) float  s_f2[1024], s_v2[1024];
    __shared__ __align__(16) float  s_b1[32], s_b2[32], s_f3[32];
    __shared__ __align__(16) float  s_bv1[32], s_bv2[32], s_v3[32];
    __shared__ __align__(16) float  s_a0[64][16];
    __shared__ float red_l[64], red_v[64];

    const int tid = threadIdx.x;
    for (int i=tid;i<640;i+=256){ s_f1[i]=Wf1[i]; s_v1[i]=Wv1[i]; }
    for (int i=tid;i<1024;i+=256){ s_f2[i]=Wf2[i]; s_v2[i]=Wv2[i]; }
    if (tid<32){ s_b1[tid]=bf1[tid]; s_b2[tid]=bf2[tid]; s_f3[tid]=Wf3[tid];
                 s_bv1[tid]=bv1[tid]; s_bv2[tid]=bv2[tid]; s_v3[tid]=Wv3[tid]; }
    if (tid<10){
        s_e1[tid] = make_float4(be1[tid], We1[tid], We1[10+tid], We1[20+tid]);
        s_e2[tid][0] = be2[tid];
        for (int e=0;e<10;++e) s_e2[tid][1+e] = We2[e*10+tid];
        s_e2[tid][11] = 0.f;
    }
    __syncthreads();

    const int j    = tid & 3;
    const int grp  = tid >> 2;
    const int act  = blockIdx.x*64 + grp;
    const bool active = act < n;
    const int actc = active ? act : (n-1);

    const float*  sp = Smat + (size_t)actc*ATOM;
    const float4* rp = (const float4*)Rraw  + (size_t)actc*ATOM;
    const float4* mp = (const float4*)Mspec + (size_t)actc*48;

    float Bh[4][10];
    float Rsum[4] = {0.f,0.f,0.f,0.f};
#pragma unroll
    for (int l=0;l<4;++l)
#pragma unroll
        for (int e=0;e<10;++e) Bh[l][e]=0.f;

#pragma unroll 1
    for (int c=0;c<4;++c) {
        const int a0 = 16*j + 4*c;
        const float4 s4 = *(const float4*)(sp + a0);
        const float4 rv0 = rp[a0+0];
        const float4 rv1 = rp[a0+1];
        const float4 rv2 = rp[a0+2];
        const float4 rv3 = rp[a0+3];
        const float4 mA = mp[12*j+3*c+0];
        const float4 mB = mp[12*j+3*c+1];
        const float4 mC = mp[12*j+3*c+2];

        const float  sv[4]  = {s4.x,s4.y,s4.z,s4.w};
        const float4 rv[4]  = {rv0,rv1,rv2,rv3};
        const float  mk[12] = {mA.x,mA.y,mA.z,mA.w,mB.x,mB.y,mB.z,mB.w,mC.x,mC.y,mC.z,mC.w};

#pragma unroll
        for (int u=0;u<4;++u) {
            const float s   = sv[u];
            const float Rl0 = s*rv[u].x, Rl1 = s*rv[u].y, Rl2 = s*rv[u].z, Rl3 = s*rv[u].w;
            const float sg0 = s*mk[3*u+0], sg1 = s*mk[3*u+1], sg2 = s*mk[3*u+2];
            float h[10];
#pragma unroll
            for (int e=0;e<10;++e) {
                const float4 w = s_e1[e];
                h[e] = fmaxf(0.f, w.x + sg0*w.y + sg1*w.z + sg2*w.w);
            }
            Rsum[0]+=Rl0; Rsum[1]+=Rl1; Rsum[2]+=Rl2; Rsum[3]+=Rl3;
#pragma unroll
            for (int e=0;e<10;++e) {
                const float he = h[e];
                Bh[0][e]+=Rl0*he; Bh[1][e]+=Rl1*he; Bh[2][e]+=Rl2*he; Bh[3][e]+=Rl3*he;
            }
            if (c==0 && u==0 && j==0) {
#pragma unroll
                for (int e=0;e<10;++e) s_a0[grp][e]=h[e];
                s_a0[grp][10]=Rl0; s_a0[grp][11]=Rl1; s_a0[grp][12]=Rl2; s_a0[grp][13]=Rl3;
            }
        }
    }

#pragma unroll
    for (int l=0;l<4;++l) {
        float v=Rsum[l]; v+=__shfl_xor(v,1); v+=__shfl_xor(v,2); Rsum[l]=v;
#pragma unroll
        for (int e=0;e<10;++e) {
            float w=Bh[l][e]; w+=__shfl_xor(w,1); w+=__shfl_xor(w,2); Bh[l][e]=w;
        }
    }

    float Df[20];
    make_D(Bh, Rsum, s_e2, Df);
    {
        const float* a0p = &s_a0[grp][0];
#pragma unroll
        for (int l=0;l<4;++l) {
            const float r0 = a0p[10+l];
            Rsum[l] -= r0;
#pragma unroll
            for (int e=0;e<10;++e) Bh[l][e] -= r0*a0p[e];
        }
    }
    float Dv[20];
    make_D(Bh, Rsum, s_e2, Dv);

    const float logit = mlp_head_quad(Df, s_f1, s_b1, s_f2, s_b2, s_f3, j) + bf3[0];
    const float vout  = mlp_head_quad(Dv, s_v1, s_bv1, s_v2, s_bv2, s_v3, j) + bv3[0];

    if (j==0) {
        red_l[grp] = active ? logit : -INFINITY;
        red_v[grp] = active ? vout  : 0.f;
        if (active) logits[act] = logit;
    }
    __syncthreads();

    if (tid < 64) {
        float m = red_l[tid];
#pragma unroll
        for (int k=1;k<64;k<<=1) m = fmaxf(m, __shfl_xor(m,k));
        float e = expf(red_l[tid] - m);
        float ssum = e, vsum = red_v[tid];
#pragma unroll
        for (int k=1;k<64;k<<=1){ ssum += __shfl_xor(ssum,k); vsum += __shfl_xor(vsum,k); }
        if (tid==0){ pmax[blockIdx.x]=m; psum[blockIdx.x]=ssum; pval[blockIdx.x]=vsum; }
    }
}

// ===========================================================================
// Kernel: merge per-block partials -> logZ, value
// ===========================================================================
__global__ __launch_bounds__(256) void k_reduce(const float* __restrict__ pmax,
                                                const float* __restrict__ psum,
                                                const float* __restrict__ pval,
                                                int nb,
                                                float* __restrict__ logZ,
                                                float* __restrict__ value_out)
{
    __shared__ float sm[256];
    const int tid = threadIdx.x;
    float m = -INFINITY;
    for (int i=tid;i<nb;i+=256) m = fmaxf(m, pmax[i]);
    sm[tid]=m; __syncthreads();
    for (int s=128;s>0;s>>=1){ if (tid<s) sm[tid]=fmaxf(sm[tid],sm[tid+s]); __syncthreads(); }
    const float M = sm[0]; __syncthreads();

    float ssum=0.f, vsum=0.f;
    for (int i=tid;i<nb;i+=256){ ssum += psum[i]*expf(pmax[i]-M); vsum += pval[i]; }
    sm[tid]=ssum; __syncthreads();
    for (int s=128;s>0;s>>=1){ if (tid<s) sm[tid]+=sm[tid+s]; __syncthreads(); }
    const float S = sm[0]; __syncthreads();

    sm[tid]=vsum; __syncthreads();
    for (int s=128;s>0;s>>=1){ if (tid<s) sm[tid]+=sm[tid+s]; __syncthreads(); }
    if (tid==0){ *logZ = M + logf(S); *value_out = sm[0]; }
}

__global__ __launch_bounds__(256) void k_apply(const float* __restrict__ logits,
                                               const float* __restrict__ logZ,
                                               float* __restrict__ out, int n)
{
    const int i = blockIdx.x*256 + threadIdx.x;
    if (i < n) out[i] = logits[i] - logZ[0];
}

extern "C" void kernel_launch(void* const* d_in, const int* in_sizes, int n_in,
                              void* d_out, int out_size, void* d_ws, size_t ws_size,
                              hipStream_t stream)
{
    const float* Smat  = (const float*)d_in[0];
    const float* Rraw  = (const float*)d_in[1];
    const float* Mspec = (const float*)d_in[2];
    const float* We1 = (const float*)d_in[3];  const float* be1 = (const float*)d_in[4];
    const float* We2 = (const float*)d_in[5];  const float* be2 = (const float*)d_in[6];
    const float* Wf1 = (const float*)d_in[7];  const float* bf1 = (const float*)d_in[8];
    const float* Wf2 = (const float*)d_in[9];  const float* bf2 = (const float*)d_in[10];
    const float* Wf3 = (const float*)d_in[11]; const float* bf3 = (const float*)d_in[12];
    const float* Wv1 = (const float*)d_in[13]; const float* bv1 = (const float*)d_in[14];
    const float* Wv2 = (const float*)d_in[15]; const float* bv2 = (const float*)d_in[16];
    const float* Wv3 = (const float*)d_in[17]; const float* bv3 = (const float*)d_in[18];

    const int n   = in_sizes[0] / ATOM;
    const int nb1 = (n + 63) / 64;            // k_desc / k_fused blocks
    const int nb2 = (n + 255) / 256;          // k_mlp blocks

    float* out = (float*)d_out;               // [n] policy, [1] value
    const size_t need = ((size_t)40*n + n + 3*(size_t)nb2 + 16) * sizeof(float);

    if (ws_size >= need) {
        float* ws     = (float*)d_ws;
        float* Dws    = ws;                    // [40*n]
        float* logits = Dws + (size_t)40*n;    // [n]
        float* pmax   = logits + n;            // [nb2]
        float* psum   = pmax + nb2;            // [nb2]
        float* pval   = psum + nb2;            // [nb2]
        float* logZ   = pval + nb2;            // [1]

        k_desc<<<nb1, 256, 0, stream>>>(Smat, Rraw, Mspec, We1, be1, We2, be2, Dws, n);
        k_mlp<<<nb2, 256, 0, stream>>>(Dws,
                                       Wf1, bf1, Wf2, bf2, Wf3, bf3,
                                       Wv1, bv1, Wv2, bv2, Wv3, bv3,
                                       logits, pmax, psum, pval, n);
        k_reduce<<<1, 256, 0, stream>>>(pmax, psum, pval, nb2, logZ, out + n);
        k_apply<<<(n + 255)/256, 256, 0, stream>>>(logits, logZ, out, n);
    } else {
        float* ws     = (float*)d_ws;
        float* logits = ws;                    // [n]
        float* pmax   = ws + n;                // [nb1]
        float* psum   = pmax + nb1;            // [nb1]
        float* pval   = psum + nb1;            // [nb1]
        float* logZ   = pval + nb1;            // [1]

        k_fused<<<nb1, 256, 0, stream>>>(Smat, Rraw, Mspec,
                                         We1, be1, We2, be2,
                                         Wf1, bf1, Wf2, bf2, Wf3, bf3,
                                         Wv1, bv1, Wv2, bv2, Wv3, bv3,
                                         logits, pmax, psum, pval, n);
        k_reduce<<<1, 256, 0, stream>>>(pmax, psum, pval, nb1, logZ, out + n);
        k_apply<<<(n + 255)/256, 256, 0, stream>>>(logits, logZ, out, n);
    }
}

// Round 5
// 121.694 us; speedup vs baseline: 3.5696x; 3.5696x over previous
//
#include <hip/hip_runtime.h>
#include <math.h>

#define ATOM 64

// ===========================================================================
// Shared device helpers
// ===========================================================================

// D[k][q] = sum_l B[l][k] * B[l][q], with B[l][q] = Rsum[l]*be2[q] + sum_e Bh[l][e]*We2[e][q]
// e2 column layout: e2[q] = { be2[q], We2[0][q], ..., We2[9][q], pad }
__device__ __forceinline__ void make_D(const float (&Bh)[4][10], const float (&Rsum)[4],
                                       const float (*e2)[12], float (&D)[20])
{
    float Bk[2][4];
#pragma unroll
    for (int k=0;k<2;++k) {
        const float4 c0 = *(const float4*)&e2[k][0];
        const float4 c1 = *(const float4*)&e2[k][4];
        const float4 c2 = *(const float4*)&e2[k][8];
#pragma unroll
        for (int l=0;l<4;++l) {
            Bk[k][l] = Rsum[l]*c0.x + Bh[l][0]*c0.y + Bh[l][1]*c0.z + Bh[l][2]*c0.w
                     + Bh[l][3]*c1.x + Bh[l][4]*c1.y + Bh[l][5]*c1.z + Bh[l][6]*c1.w
                     + Bh[l][7]*c2.x + Bh[l][8]*c2.y + Bh[l][9]*c2.z;
        }
    }
#pragma unroll
    for (int q=0;q<10;++q) {
        const float4 c0 = *(const float4*)&e2[q][0];
        const float4 c1 = *(const float4*)&e2[q][4];
        const float4 c2 = *(const float4*)&e2[q][8];
        float Bq[4];
#pragma unroll
        for (int l=0;l<4;++l) {
            Bq[l] = Rsum[l]*c0.x + Bh[l][0]*c0.y + Bh[l][1]*c0.z + Bh[l][2]*c0.w
                  + Bh[l][3]*c1.x + Bh[l][4]*c1.y + Bh[l][5]*c1.z + Bh[l][6]*c1.w
                  + Bh[l][7]*c2.x + Bh[l][8]*c2.y + Bh[l][9]*c2.z;
        }
        D[q]    = Bk[0][0]*Bq[0]+Bk[0][1]*Bq[1]+Bk[0][2]*Bq[2]+Bk[0][3]*Bq[3];
        D[10+q] = Bk[1][0]*Bq[0]+Bk[1][1]*Bq[1]+Bk[1][2]*Bq[2]+Bk[1][3]*Bq[3];
    }
}

// quad-cooperative MLP head (used by fused fallback only)
__device__ __forceinline__ float mlp_head_quad(const float* __restrict__ x,
                                          const float* __restrict__ w1, const float* __restrict__ b1,
                                          const float* __restrict__ w2, const float* __restrict__ b2,
                                          const float* __restrict__ w3, int j)
{
    float h1[8];
    {
        float4 ba = *(const float4*)(b1 + 8*j);
        float4 bb = *(const float4*)(b1 + 8*j + 4);
        h1[0]=ba.x; h1[1]=ba.y; h1[2]=ba.z; h1[3]=ba.w;
        h1[4]=bb.x; h1[5]=bb.y; h1[6]=bb.z; h1[7]=bb.w;
    }
#pragma unroll
    for (int d=0; d<20; ++d) {
        float4 w0 = *(const float4*)(w1 + d*32 + 8*j);
        float4 w4 = *(const float4*)(w1 + d*32 + 8*j + 4);
        float xv = x[d];
        h1[0] += xv*w0.x; h1[1] += xv*w0.y; h1[2] += xv*w0.z; h1[3] += xv*w0.w;
        h1[4] += xv*w4.x; h1[5] += xv*w4.y; h1[6] += xv*w4.z; h1[7] += xv*w4.w;
    }
#pragma unroll
    for (int o=0;o<8;++o) h1[o] = fmaxf(h1[o], 0.f);

    float s = 0.f;
#pragma unroll
    for (int half=0; half<2; ++half) {
        float p[16];
#pragma unroll
        for (int q=0;q<16;++q) p[q] = 0.f;
#pragma unroll
        for (int o=0;o<8;++o) {
            const float* row = w2 + (8*j + o)*32 + 16*half;
            float hv = h1[o];
#pragma unroll
            for (int q=0;q<4;++q) {
                float4 w = *(const float4*)(row + 4*q);
                p[4*q+0] += hv*w.x; p[4*q+1] += hv*w.y;
                p[4*q+2] += hv*w.z; p[4*q+3] += hv*w.w;
            }
        }
#pragma unroll
        for (int q=0;q<16;++q) { p[q] += __shfl_xor(p[q],1); p[q] += __shfl_xor(p[q],2); }
#pragma unroll
        for (int q=0;q<4;++q) {
            float4 bq = *(const float4*)(b2 + 16*half + 4*q);
            float4 wq = *(const float4*)(w3 + 16*half + 4*q);
            s += fmaxf(p[4*q+0]+bq.x, 0.f)*wq.x;
            s += fmaxf(p[4*q+1]+bq.y, 0.f)*wq.y;
            s += fmaxf(p[4*q+2]+bq.z, 0.f)*wq.z;
            s += fmaxf(p[4*q+3]+bq.w, 0.f)*wq.w;
        }
    }
    return s;
}

// full per-thread MLP head: x[20] -> 32 -> 32 -> 1 (bias3 added by caller)
__device__ __forceinline__ float full_head(const float (&x)[20],
                                           const float* __restrict__ w1, const float* __restrict__ b1,
                                           const float* __restrict__ w2, const float* __restrict__ b2,
                                           const float* __restrict__ w3)
{
    float h1[32];
#pragma unroll
    for (int q=0;q<8;++q) {
        float4 b = *(const float4*)(b1 + 4*q);
        h1[4*q+0]=b.x; h1[4*q+1]=b.y; h1[4*q+2]=b.z; h1[4*q+3]=b.w;
    }
#pragma unroll
    for (int d=0; d<20; ++d) {
        const float xv = x[d];
        const float* row = w1 + d*32;
#pragma unroll
        for (int q=0;q<8;++q) {
            float4 w = *(const float4*)(row + 4*q);
            h1[4*q+0] += xv*w.x; h1[4*q+1] += xv*w.y;
            h1[4*q+2] += xv*w.z; h1[4*q+3] += xv*w.w;
        }
    }
    float p[32];
#pragma unroll
    for (int q=0;q<8;++q) {
        float4 b = *(const float4*)(b2 + 4*q);
        p[4*q+0]=b.x; p[4*q+1]=b.y; p[4*q+2]=b.z; p[4*q+3]=b.w;
    }
#pragma unroll
    for (int o=0;o<32;++o) {
        const float hv = fmaxf(h1[o], 0.f);
        const float* row = w2 + o*32;
#pragma unroll
        for (int q=0;q<8;++q) {
            float4 w = *(const float4*)(row + 4*q);
            p[4*q+0] += hv*w.x; p[4*q+1] += hv*w.y;
            p[4*q+2] += hv*w.z; p[4*q+3] += hv*w.w;
        }
    }
    float s = 0.f;
#pragma unroll
    for (int q=0;q<8;++q) {
        float4 wq = *(const float4*)(w3 + 4*q);
        s += fmaxf(p[4*q+0], 0.f)*wq.x;
        s += fmaxf(p[4*q+1], 0.f)*wq.y;
        s += fmaxf(p[4*q+2], 0.f)*wq.z;
        s += fmaxf(p[4*q+3], 0.f)*wq.w;
    }
    return s;
}

// ===========================================================================
// Kernel A: descriptor only. 4 lanes/action, 64 actions/block.
// Writes Df/Dv per action into Dws, transposed layout Dws[c*n + act], c=0..39.
// __launch_bounds__(256) — plain: allocator free to pick its no-spill budget
// (default 1024-thread assumption clamps VGPR to 64 and spills; R4 evidence).
// ===========================================================================
__global__ __launch_bounds__(256) void k_desc(
    const float* __restrict__ Smat, const float* __restrict__ Rraw, const float* __restrict__ Mspec,
    const float* __restrict__ We1, const float* __restrict__ be1,
    const float* __restrict__ We2, const float* __restrict__ be2,
    float* __restrict__ Dws, int n)
{
    __shared__ __align__(16) float4 s_e1[10];     // {b_e1[e], We1[0][e], We1[1][e], We1[2][e]}
    __shared__ __align__(16) float  s_e2[10][12]; // col q: {b_e2[q], We2[0..9][q], pad}
    __shared__ __align__(16) float  s_a0[64][16]; // per-action atom-0 {h0[10], R0[4]}

    const int tid = threadIdx.x;
    if (tid<10){
        s_e1[tid] = make_float4(be1[tid], We1[tid], We1[10+tid], We1[20+tid]);
        s_e2[tid][0] = be2[tid];
        for (int e=0;e<10;++e) s_e2[tid][1+e] = We2[e*10+tid];
        s_e2[tid][11] = 0.f;
    }
    __syncthreads();

    const int j    = tid & 3;
    const int grp  = tid >> 2;
    const int act  = blockIdx.x*64 + grp;
    const bool active = act < n;
    const int actc = active ? act : (n-1);

    const float*  sp = Smat + (size_t)actc*ATOM;
    const float4* rp = (const float4*)Rraw  + (size_t)actc*ATOM;
    const float4* mp = (const float4*)Mspec + (size_t)actc*48;

    float Bh[4][10];
    float Rsum[4] = {0.f,0.f,0.f,0.f};
#pragma unroll
    for (int l=0;l<4;++l)
#pragma unroll
        for (int e=0;e<10;++e) Bh[l][e]=0.f;

#pragma unroll 1
    for (int c=0;c<4;++c) {
        const int a0 = 16*j + 4*c;
        const float4 s4 = *(const float4*)(sp + a0);
        const float4 rv0 = rp[a0+0];
        const float4 rv1 = rp[a0+1];
        const float4 rv2 = rp[a0+2];
        const float4 rv3 = rp[a0+3];
        const float4 mA = mp[12*j+3*c+0];
        const float4 mB = mp[12*j+3*c+1];
        const float4 mC = mp[12*j+3*c+2];

        const float  sv[4]  = {s4.x,s4.y,s4.z,s4.w};
        const float4 rv[4]  = {rv0,rv1,rv2,rv3};
        const float  mk[12] = {mA.x,mA.y,mA.z,mA.w,mB.x,mB.y,mB.z,mB.w,mC.x,mC.y,mC.z,mC.w};

#pragma unroll
        for (int u=0;u<4;++u) {
            const float s   = sv[u];
            const float Rl0 = s*rv[u].x, Rl1 = s*rv[u].y, Rl2 = s*rv[u].z, Rl3 = s*rv[u].w;
            const float sg0 = s*mk[3*u+0], sg1 = s*mk[3*u+1], sg2 = s*mk[3*u+2];
            float h[10];
#pragma unroll
            for (int e=0;e<10;++e) {
                const float4 w = s_e1[e];
                h[e] = fmaxf(0.f, w.x + sg0*w.y + sg1*w.z + sg2*w.w);
            }
            Rsum[0]+=Rl0; Rsum[1]+=Rl1; Rsum[2]+=Rl2; Rsum[3]+=Rl3;
#pragma unroll
            for (int e=0;e<10;++e) {
                const float he = h[e];
                Bh[0][e]+=Rl0*he; Bh[1][e]+=Rl1*he; Bh[2][e]+=Rl2*he; Bh[3][e]+=Rl3*he;
            }
            if (c==0 && u==0 && j==0) {
#pragma unroll
                for (int e=0;e<10;++e) s_a0[grp][e]=h[e];
                s_a0[grp][10]=Rl0; s_a0[grp][11]=Rl1; s_a0[grp][12]=Rl2; s_a0[grp][13]=Rl3;
            }
        }
    }

#pragma unroll
    for (int l=0;l<4;++l) {
        float v=Rsum[l]; v+=__shfl_xor(v,1); v+=__shfl_xor(v,2); Rsum[l]=v;
#pragma unroll
        for (int e=0;e<10;++e) {
            float w=Bh[l][e]; w+=__shfl_xor(w,1); w+=__shfl_xor(w,2); Bh[l][e]=w;
        }
    }

    float Df[20];
    make_D(Bh, Rsum, s_e2, Df);

    {
        const float* a0p = &s_a0[grp][0];
#pragma unroll
        for (int l=0;l<4;++l) {
            const float r0 = a0p[10+l];
            Rsum[l] -= r0;
#pragma unroll
            for (int e=0;e<10;++e) Bh[l][e] -= r0*a0p[e];
        }
    }
    float Dv[20];
    make_D(Bh, Rsum, s_e2, Dv);

    if (active) {
        const size_t N = (size_t)n;
        if (j==0) {
#pragma unroll
            for (int d=0;d<10;++d) Dws[(size_t)d*N + act] = Df[d];
        } else if (j==1) {
#pragma unroll
            for (int d=0;d<10;++d) Dws[(size_t)(10+d)*N + act] = Df[10+d];
        } else if (j==2) {
#pragma unroll
            for (int d=0;d<10;++d) Dws[(size_t)(20+d)*N + act] = Dv[d];
        } else {
#pragma unroll
            for (int d=0;d<10;++d) Dws[(size_t)(30+d)*N + act] = Dv[10+d];
        }
    }
}

// ===========================================================================
// Kernel B: 1 thread = 1 action, both heads; weights in LDS (uniform broadcast).
// Emits logits + per-block softmax/value partials (256 actions/block).
// ===========================================================================
__global__ __launch_bounds__(256) void k_mlp(
    const float* __restrict__ Dws,
    const float* __restrict__ Wf1, const float* __restrict__ bf1,
    const float* __restrict__ Wf2, const float* __restrict__ bf2,
    const float* __restrict__ Wf3, const float* __restrict__ bf3,
    const float* __restrict__ Wv1, const float* __restrict__ bv1,
    const float* __restrict__ Wv2, const float* __restrict__ bv2,
    const float* __restrict__ Wv3, const float* __restrict__ bv3,
    float* __restrict__ logits, float* __restrict__ pmax,
    float* __restrict__ psum, float* __restrict__ pval, int n)
{
    __shared__ __align__(16) float s_f1[640], s_v1[640];
    __shared__ __align__(16) float s_f2[1024], s_v2[1024];
    __shared__ __align__(16) float s_b1[32], s_b2[32], s_f3[32];
    __shared__ __align__(16) float s_bv1[32], s_bv2[32], s_v3[32];
    __shared__ float red_l[256], red_v[256];

    const int tid = threadIdx.x;
    for (int i=tid;i<640;i+=256){ s_f1[i]=Wf1[i]; s_v1[i]=Wv1[i]; }
    for (int i=tid;i<1024;i+=256){ s_f2[i]=Wf2[i]; s_v2[i]=Wv2[i]; }
    if (tid<32){ s_b1[tid]=bf1[tid]; s_b2[tid]=bf2[tid]; s_f3[tid]=Wf3[tid];
                 s_bv1[tid]=bv1[tid]; s_bv2[tid]=bv2[tid]; s_v3[tid]=Wv3[tid]; }
    __syncthreads();

    const int i = blockIdx.x*256 + tid;
    const bool active = i < n;
    const int ic = active ? i : (n-1);
    const size_t N = (size_t)n;

    float x[20];
#pragma unroll
    for (int c=0;c<20;++c) x[c] = Dws[(size_t)c*N + ic];
    const float logit = full_head(x, s_f1, s_b1, s_f2, s_b2, s_f3) + bf3[0];

#pragma unroll
    for (int c=0;c<20;++c) x[c] = Dws[(size_t)(20+c)*N + ic];
    const float vout  = full_head(x, s_v1, s_bv1, s_v2, s_bv2, s_v3) + bv3[0];

    if (active) logits[i] = logit;
    red_l[tid] = active ? logit : -INFINITY;
    red_v[tid] = active ? vout  : 0.f;
    __syncthreads();

    if (tid < 64) {
        float m = red_l[tid];
#pragma unroll
        for (int k=1;k<4;++k) m = fmaxf(m, red_l[tid+64*k]);
#pragma unroll
        for (int k=1;k<64;k<<=1) m = fmaxf(m, __shfl_xor(m,k));
        float ssum = 0.f, vsum = 0.f;
#pragma unroll
        for (int k=0;k<4;++k) {
            ssum += expf(red_l[tid+64*k] - m);   // -inf -> 0
            vsum += red_v[tid+64*k];
        }
#pragma unroll
        for (int k=1;k<64;k<<=1){ ssum += __shfl_xor(ssum,k); vsum += __shfl_xor(vsum,k); }
        if (tid==0){ pmax[blockIdx.x]=m; psum[blockIdx.x]=ssum; pval[blockIdx.x]=vsum; }
    }
}

// ===========================================================================
// Fused fallback (R3 structure, plain 256 bound — the proven-safe config)
// ===========================================================================
__global__ __launch_bounds__(256) void k_fused(
    const float* __restrict__ Smat, const float* __restrict__ Rraw, const float* __restrict__ Mspec,
    const float* __restrict__ We1, const float* __restrict__ be1,
    const float* __restrict__ We2, const float* __restrict__ be2,
    const float* __restrict__ Wf1, const float* __restrict__ bf1,
    const float* __restrict__ Wf2, const float* __restrict__ bf2,
    const float* __restrict__ Wf3, const float* __restrict__ bf3,
    const float* __restrict__ Wv1, const float* __restrict__ bv1,
    const float* __restrict__ Wv2, const float* __restrict__ bv2,
    const float* __restrict__ Wv3, const float* __restrict__ bv3,
    float* __restrict__ logits, float* __restrict__ pmax,
    float* __restrict__ psum, float* __restrict__ pval, int n)
{
    __shared__ __align__(16) float4 s_e1[10];
    __shared__ __align__(16) float  s_e2[10][12];
    __shared__ __align__(16) float  s_f1[640], s_v1[640];
    __shared__ __align__(16) float  s_f2[1024], s_v2[1024];
    __shared__ __align__(16) float  s_b1[32], s_b2[32], s_f3[32];
    __shared__ __align__(16) float  s_bv1[32], s_bv2[32], s_v3[32];
    __shared__ __align__(16) float  s_a0[64][16];
    __shared__ float red_l[64], red_v[64];

    const int tid = threadIdx.x;
    for (int i=tid;i<640;i+=256){ s_f1[i]=Wf1[i]; s_v1[i]=Wv1[i]; }
    for (int i=tid;i<1024;i+=256){ s_f2[i]=Wf2[i]; s_v2[i]=Wv2[i]; }
    if (tid<32){ s_b1[tid]=bf1[tid]; s_b2[tid]=bf2[tid]; s_f3[tid]=Wf3[tid];
                 s_bv1[tid]=bv1[tid]; s_bv2[tid]=bv2[tid]; s_v3[tid]=Wv3[tid]; }
    if (tid<10){
        s_e1[tid] = make_float4(be1[tid], We1[tid], We1[10+tid], We1[20+tid]);
        s_e2[tid][0] = be2[tid];
        for (int e=0;e<10;++e) s_e2[tid][1+e] = We2[e*10+tid];
        s_e2[tid][11] = 0.f;
    }
    __syncthreads();

    const int j    = tid & 3;
    const int grp  = tid >> 2;
    const int act  = blockIdx.x*64 + grp;
    const bool active = act < n;
    const int actc = active ? act : (n-1);

    const float*  sp = Smat + (size_t)actc*ATOM;
    const float4* rp = (const float4*)Rraw  + (size_t)actc*ATOM;
    const float4* mp = (const float4*)Mspec + (size_t)actc*48;

    float Bh[4][10];
    float Rsum[4] = {0.f,0.f,0.f,0.f};
#pragma unroll
    for (int l=0;l<4;++l)
#pragma unroll
        for (int e=0;e<10;++e) Bh[l][e]=0.f;

#pragma unroll 1
    for (int c=0;c<4;++c) {
        const int a0 = 16*j + 4*c;
        const float4 s4 = *(const float4*)(sp + a0);
        const float4 rv0 = rp[a0+0];
        const float4 rv1 = rp[a0+1];
        const float4 rv2 = rp[a0+2];
        const float4 rv3 = rp[a0+3];
        const float4 mA = mp[12*j+3*c+0];
        const float4 mB = mp[12*j+3*c+1];
        const float4 mC = mp[12*j+3*c+2];

        const float  sv[4]  = {s4.x,s4.y,s4.z,s4.w};
        const float4 rv[4]  = {rv0,rv1,rv2,rv3};
        const float  mk[12] = {mA.x,mA.y,mA.z,mA.w,mB.x,mB.y,mB.z,mB.w,mC.x,mC.y,mC.z,mC.w};

#pragma unroll
        for (int u=0;u<4;++u) {
            const float s   = sv[u];
            const float Rl0 = s*rv[u].x, Rl1 = s*rv[u].y, Rl2 = s*rv[u].z, Rl3 = s*rv[u].w;
            const float sg0 = s*mk[3*u+0], sg1 = s*mk[3*u+1], sg2 = s*mk[3*u+2];
            float h[10];
#pragma unroll
            for (int e=0;e<10;++e) {
                const float4 w = s_e1[e];
                h[e] = fmaxf(0.f, w.x + sg0*w.y + sg1*w.z + sg2*w.w);
            }
            Rsum[0]+=Rl0; Rsum[1]+=Rl1; Rsum[2]+=Rl2; Rsum[3]+=Rl3;
#pragma unroll
            for (int e=0;e<10;++e) {
                const float he = h[e];
                Bh[0][e]+=Rl0*he; Bh[1][e]+=Rl1*he; Bh[2][e]+=Rl2*he; Bh[3][e]+=Rl3*he;
            }
            if (c==0 && u==0 && j==0) {
#pragma unroll
                for (int e=0;e<10;++e) s_a0[grp][e]=h[e];
                s_a0[grp][10]=Rl0; s_a0[grp][11]=Rl1; s_a0[grp][12]=Rl2; s_a0[grp][13]=Rl3;
            }
        }
    }

#pragma unroll
    for (int l=0;l<4;++l) {
        float v=Rsum[l]; v+=__shfl_xor(v,1); v+=__shfl_xor(v,2); Rsum[l]=v;
#pragma unroll
        for (int e=0;e<10;++e) {
            float w=Bh[l][e]; w+=__shfl_xor(w,1); w+=__shfl_xor(w,2); Bh[l][e]=w;
        }
    }

    float Df[20];
    make_D(Bh, Rsum, s_e2, Df);
    {
        const float* a0p = &s_a0[grp][0];
#pragma unroll
        for (int l=0;l<4;++l) {
            const float r0 = a0p[10+l];
            Rsum[l] -= r0;
#pragma unroll
            for (int e=0;e<10;++e) Bh[l][e] -= r0*a0p[e];
        }
    }
    float Dv[20];
    make_D(Bh, Rsum, s_e2, Dv);

    const float logit = mlp_head_quad(Df, s_f1, s_b1, s_f2, s_b2, s_f3, j) + bf3[0];
    const float vout  = mlp_head_quad(Dv, s_v1, s_bv1, s_v2, s_bv2, s_v3, j) + bv3[0];

    if (j==0) {
        red_l[grp] = active ? logit : -INFINITY;
        red_v[grp] = active ? vout  : 0.f;
        if (active) logits[act] = logit;
    }
    __syncthreads();

    if (tid < 64) {
        float m = red_l[tid];
#pragma unroll
        for (int k=1;k<64;k<<=1) m = fmaxf(m, __shfl_xor(m,k));
        float e = expf(red_l[tid] - m);
        float ssum = e, vsum = red_v[tid];
#pragma unroll
        for (int k=1;k<64;k<<=1){ ssum += __shfl_xor(ssum,k); vsum += __shfl_xor(vsum,k); }
        if (tid==0){ pmax[blockIdx.x]=m; psum[blockIdx.x]=ssum; pval[blockIdx.x]=vsum; }
    }
}

// ===========================================================================
// Kernel: merge per-block partials -> logZ, value
// ===========================================================================
__global__ __launch_bounds__(256) void k_reduce(const float* __restrict__ pmax,
                                                const float* __restrict__ psum,
                                                const float* __restrict__ pval,
                                                int nb,
                                                float* __restrict__ logZ,
                                                float* __restrict__ value_out)
{
    __shared__ float sm[256];
    const int tid = threadIdx.x;
    float m = -INFINITY;
    for (int i=tid;i<nb;i+=256) m = fmaxf(m, pmax[i]);
    sm[tid]=m; __syncthreads();
    for (int s=128;s>0;s>>=1){ if (tid<s) sm[tid]=fmaxf(sm[tid],sm[tid+s]); __syncthreads(); }
    const float M = sm[0]; __syncthreads();

    float ssum=0.f, vsum=0.f;
    for (int i=tid;i<nb;i+=256){ ssum += psum[i]*expf(pmax[i]-M); vsum += pval[i]; }
    sm[tid]=ssum; __syncthreads();
    for (int s=128;s>0;s>>=1){ if (tid<s) sm[tid]+=sm[tid+s]; __syncthreads(); }
    const float S = sm[0]; __syncthreads();

    sm[tid]=vsum; __syncthreads();
    for (int s=128;s>0;s>>=1){ if (tid<s) sm[tid]+=sm[tid+s]; __syncthreads(); }
    if (tid==0){ *logZ = M + logf(S); *value_out = sm[0]; }
}

__global__ __launch_bounds__(256) void k_apply(const float* __restrict__ logits,
                                               const float* __restrict__ logZ,
                                               float* __restrict__ out, int n)
{
    const int i = blockIdx.x*256 + threadIdx.x;
    if (i < n) out[i] = logits[i] - logZ[0];
}

extern "C" void kernel_launch(void* const* d_in, const int* in_sizes, int n_in,
                              void* d_out, int out_size, void* d_ws, size_t ws_size,
                              hipStream_t stream)
{
    const float* Smat  = (const float*)d_in[0];
    const float* Rraw  = (const float*)d_in[1];
    const float* Mspec = (const float*)d_in[2];
    const float* We1 = (const float*)d_in[3];  const float* be1 = (const float*)d_in[4];
    const float* We2 = (const float*)d_in[5];  const float* be2 = (const float*)d_in[6];
    const float* Wf1 = (const float*)d_in[7];  const float* bf1 = (const float*)d_in[8];
    const float* Wf2 = (const float*)d_in[9];  const float* bf2 = (const float*)d_in[10];
    const float* Wf3 = (const float*)d_in[11]; const float* bf3 = (const float*)d_in[12];
    const float* Wv1 = (const float*)d_in[13]; const float* bv1 = (const float*)d_in[14];
    const float* Wv2 = (const float*)d_in[15]; const float* bv2 = (const float*)d_in[16];
    const float* Wv3 = (const float*)d_in[17]; const float* bv3 = (const float*)d_in[18];

    const int n   = in_sizes[0] / ATOM;
    const int nb1 = (n + 63) / 64;            // k_desc / k_fused blocks
    const int nb2 = (n + 255) / 256;          // k_mlp blocks

    float* out = (float*)d_out;               // [n] policy, [1] value
    const size_t need = ((size_t)40*n + n + 3*(size_t)nb2 + 16) * sizeof(float);

    if (ws_size >= need) {
        float* ws     = (float*)d_ws;
        float* Dws    = ws;                    // [40*n]
        float* logits = Dws + (size_t)40*n;    // [n]
        float* pmax   = logits + n;            // [nb2]
        float* psum   = pmax + nb2;            // [nb2]
        float* pval   = psum + nb2;            // [nb2]
        float* logZ   = pval + nb2;            // [1]

        k_desc<<<nb1, 256, 0, stream>>>(Smat, Rraw, Mspec, We1, be1, We2, be2, Dws, n);
        k_mlp<<<nb2, 256, 0, stream>>>(Dws,
                                       Wf1, bf1, Wf2, bf2, Wf3, bf3,
                                       Wv1, bv1, Wv2, bv2, Wv3, bv3,
                                       logits, pmax, psum, pval, n);
        k_reduce<<<1, 256, 0, stream>>>(pmax, psum, pval, nb2, logZ, out + n);
        k_apply<<<(n + 255)/256, 256, 0, stream>>>(logits, logZ, out, n);
    } else {
        float* ws     = (float*)d_ws;
        float* logits = ws;                    // [n]
        float* pmax   = ws + n;                // [nb1]
        float* psum   = pmax + nb1;            // [nb1]
        float* pval   = psum + nb1;            // [nb1]
        float* logZ   = pval + nb1;            // [1]

        k_fused<<<nb1, 256, 0, stream>>>(Smat, Rraw, Mspec,
                                         We1, be1, We2, be2,
                                         Wf1, bf1, Wf2, bf2, Wf3, bf3,
                                         Wv1, bv1, Wv2, bv2, Wv3, bv3,
                                         logits, pmax, psum, pval, n);
        k_reduce<<<1, 256, 0, stream>>>(pmax, psum, pval, nb1, logZ, out + n);
        k_apply<<<(n + 255)/256, 256, 0, stream>>>(logits, logZ, out, n);
    }
}

// Round 6
// 117.807 us; speedup vs baseline: 3.6874x; 1.0330x over previous
//
#include <hip/hip_runtime.h>
#include <math.h>

#define ATOM 64

// ===========================================================================
// Shared device helpers
// ===========================================================================

// D[k][q] = sum_l B[l][k] * B[l][q], with B[l][q] = Rsum[l]*be2[q] + sum_e Bh[l][e]*We2[e][q]
// e2 column layout: e2[q] = { be2[q], We2[0][q], ..., We2[9][q], pad }
__device__ __forceinline__ void make_D(const float (&Bh)[4][10], const float (&Rsum)[4],
                                       const float (*e2)[12], float (&D)[20])
{
    float Bk[2][4];
#pragma unroll
    for (int k=0;k<2;++k) {
        const float4 c0 = *(const float4*)&e2[k][0];
        const float4 c1 = *(const float4*)&e2[k][4];
        const float4 c2 = *(const float4*)&e2[k][8];
#pragma unroll
        for (int l=0;l<4;++l) {
            Bk[k][l] = Rsum[l]*c0.x + Bh[l][0]*c0.y + Bh[l][1]*c0.z + Bh[l][2]*c0.w
                     + Bh[l][3]*c1.x + Bh[l][4]*c1.y + Bh[l][5]*c1.z + Bh[l][6]*c1.w
                     + Bh[l][7]*c2.x + Bh[l][8]*c2.y + Bh[l][9]*c2.z;
        }
    }
#pragma unroll
    for (int q=0;q<10;++q) {
        const float4 c0 = *(const float4*)&e2[q][0];
        const float4 c1 = *(const float4*)&e2[q][4];
        const float4 c2 = *(const float4*)&e2[q][8];
        float Bq[4];
#pragma unroll
        for (int l=0;l<4;++l) {
            Bq[l] = Rsum[l]*c0.x + Bh[l][0]*c0.y + Bh[l][1]*c0.z + Bh[l][2]*c0.w
                  + Bh[l][3]*c1.x + Bh[l][4]*c1.y + Bh[l][5]*c1.z + Bh[l][6]*c1.w
                  + Bh[l][7]*c2.x + Bh[l][8]*c2.y + Bh[l][9]*c2.z;
        }
        D[q]    = Bk[0][0]*Bq[0]+Bk[0][1]*Bq[1]+Bk[0][2]*Bq[2]+Bk[0][3]*Bq[3];
        D[10+q] = Bk[1][0]*Bq[0]+Bk[1][1]*Bq[1]+Bk[1][2]*Bq[2]+Bk[1][3]*Bq[3];
    }
}

// quad-cooperative MLP head (used by fused fallback only)
__device__ __forceinline__ float mlp_head_quad(const float* __restrict__ x,
                                          const float* __restrict__ w1, const float* __restrict__ b1,
                                          const float* __restrict__ w2, const float* __restrict__ b2,
                                          const float* __restrict__ w3, int j)
{
    float h1[8];
    {
        float4 ba = *(const float4*)(b1 + 8*j);
        float4 bb = *(const float4*)(b1 + 8*j + 4);
        h1[0]=ba.x; h1[1]=ba.y; h1[2]=ba.z; h1[3]=ba.w;
        h1[4]=bb.x; h1[5]=bb.y; h1[6]=bb.z; h1[7]=bb.w;
    }
#pragma unroll
    for (int d=0; d<20; ++d) {
        float4 w0 = *(const float4*)(w1 + d*32 + 8*j);
        float4 w4 = *(const float4*)(w1 + d*32 + 8*j + 4);
        float xv = x[d];
        h1[0] += xv*w0.x; h1[1] += xv*w0.y; h1[2] += xv*w0.z; h1[3] += xv*w0.w;
        h1[4] += xv*w4.x; h1[5] += xv*w4.y; h1[6] += xv*w4.z; h1[7] += xv*w4.w;
    }
#pragma unroll
    for (int o=0;o<8;++o) h1[o] = fmaxf(h1[o], 0.f);

    float s = 0.f;
#pragma unroll
    for (int half=0; half<2; ++half) {
        float p[16];
#pragma unroll
        for (int q=0;q<16;++q) p[q] = 0.f;
#pragma unroll
        for (int o=0;o<8;++o) {
            const float* row = w2 + (8*j + o)*32 + 16*half;
            float hv = h1[o];
#pragma unroll
            for (int q=0;q<4;++q) {
                float4 w = *(const float4*)(row + 4*q);
                p[4*q+0] += hv*w.x; p[4*q+1] += hv*w.y;
                p[4*q+2] += hv*w.z; p[4*q+3] += hv*w.w;
            }
        }
#pragma unroll
        for (int q=0;q<16;++q) { p[q] += __shfl_xor(p[q],1); p[q] += __shfl_xor(p[q],2); }
#pragma unroll
        for (int q=0;q<4;++q) {
            float4 bq = *(const float4*)(b2 + 16*half + 4*q);
            float4 wq = *(const float4*)(w3 + 16*half + 4*q);
            s += fmaxf(p[4*q+0]+bq.x, 0.f)*wq.x;
            s += fmaxf(p[4*q+1]+bq.y, 0.f)*wq.y;
            s += fmaxf(p[4*q+2]+bq.z, 0.f)*wq.z;
            s += fmaxf(p[4*q+3]+bq.w, 0.f)*wq.w;
        }
    }
    return s;
}

// full per-thread MLP head: x[20] -> 32 -> 32 -> 1 (bias3 added by caller)
__device__ __forceinline__ float full_head(const float (&x)[20],
                                           const float* __restrict__ w1, const float* __restrict__ b1,
                                           const float* __restrict__ w2, const float* __restrict__ b2,
                                           const float* __restrict__ w3)
{
    float h1[32];
#pragma unroll
    for (int q=0;q<8;++q) {
        float4 b = *(const float4*)(b1 + 4*q);
        h1[4*q+0]=b.x; h1[4*q+1]=b.y; h1[4*q+2]=b.z; h1[4*q+3]=b.w;
    }
#pragma unroll
    for (int d=0; d<20; ++d) {
        const float xv = x[d];
        const float* row = w1 + d*32;
#pragma unroll
        for (int q=0;q<8;++q) {
            float4 w = *(const float4*)(row + 4*q);
            h1[4*q+0] += xv*w.x; h1[4*q+1] += xv*w.y;
            h1[4*q+2] += xv*w.z; h1[4*q+3] += xv*w.w;
        }
    }
    float p[32];
#pragma unroll
    for (int q=0;q<8;++q) {
        float4 b = *(const float4*)(b2 + 4*q);
        p[4*q+0]=b.x; p[4*q+1]=b.y; p[4*q+2]=b.z; p[4*q+3]=b.w;
    }
#pragma unroll
    for (int o=0;o<32;++o) {
        const float hv = fmaxf(h1[o], 0.f);
        const float* row = w2 + o*32;
#pragma unroll
        for (int q=0;q<8;++q) {
            float4 w = *(const float4*)(row + 4*q);
            p[4*q+0] += hv*w.x; p[4*q+1] += hv*w.y;
            p[4*q+2] += hv*w.z; p[4*q+3] += hv*w.w;
        }
    }
    float s = 0.f;
#pragma unroll
    for (int q=0;q<8;++q) {
        float4 wq = *(const float4*)(w3 + 4*q);
        s += fmaxf(p[4*q+0], 0.f)*wq.x;
        s += fmaxf(p[4*q+1], 0.f)*wq.y;
        s += fmaxf(p[4*q+2], 0.f)*wq.z;
        s += fmaxf(p[4*q+3], 0.f)*wq.w;
    }
    return s;
}

// ===========================================================================
// Kernel A: descriptor only. 4 lanes/action, 64 actions/block.
// R6: 2-deep load pipeline, e1 in registers (uniform->SGPR), make_D split by lane.
// Lane j computes+stores rows [10j,10j+10) of Dws (k=j&1, head=j>>1).
// ===========================================================================
__global__ __launch_bounds__(256) void k_desc(
    const float* __restrict__ Smat, const float* __restrict__ Rraw, const float* __restrict__ Mspec,
    const float* __restrict__ We1, const float* __restrict__ be1,
    const float* __restrict__ We2, const float* __restrict__ be2,
    float* __restrict__ Dws, int n)
{
    __shared__ __align__(16) float s_e2[10][12]; // col q: {b_e2[q], We2[0..9][q], pad}
    __shared__ __align__(16) float s_a0[64][16]; // per-action atom-0 {h0[10], R0[4]}

    const int tid = threadIdx.x;
    if (tid<10){
        s_e2[tid][0] = be2[tid];
        for (int e=0;e<10;++e) s_e2[tid][1+e] = We2[e*10+tid];
        s_e2[tid][11] = 0.f;
    }
    __syncthreads();

    // e1 weights: uniform loads -> scalar registers (no LDS in hot loop)
    float e1w[10][4];
#pragma unroll
    for (int e=0;e<10;++e){
        e1w[e][0]=be1[e]; e1w[e][1]=We1[e]; e1w[e][2]=We1[10+e]; e1w[e][3]=We1[20+e];
    }

    const int j    = tid & 3;
    const int grp  = tid >> 2;
    const int act  = blockIdx.x*64 + grp;
    const bool active = act < n;
    const int actc = active ? act : (n-1);

    const float4* sp4 = (const float4*)(Smat + (size_t)actc*ATOM);
    const float4* rp  = (const float4*)Rraw  + (size_t)actc*ATOM;
    const float4* mp  = (const float4*)Mspec + (size_t)actc*48;

    float Bh[4][10];
    float Rsum[4] = {0.f,0.f,0.f,0.f};
#pragma unroll
    for (int l=0;l<4;++l)
#pragma unroll
        for (int e=0;e<10;++e) Bh[l][e]=0.f;

    auto step = [&](const float4& s4, const float4& rv0, const float4& rv1,
                    const float4& rv2, const float4& rv3,
                    const float4& mA, const float4& mB, const float4& mC, bool first){
        const float  sv[4]  = {s4.x,s4.y,s4.z,s4.w};
        const float4 rv[4]  = {rv0,rv1,rv2,rv3};
        const float  mk[12] = {mA.x,mA.y,mA.z,mA.w,mB.x,mB.y,mB.z,mB.w,mC.x,mC.y,mC.z,mC.w};
#pragma unroll
        for (int u=0;u<4;++u){
            const float s   = sv[u];
            const float Rl0 = s*rv[u].x, Rl1 = s*rv[u].y, Rl2 = s*rv[u].z, Rl3 = s*rv[u].w;
            const float sg0 = s*mk[3*u+0], sg1 = s*mk[3*u+1], sg2 = s*mk[3*u+2];
            float h[10];
#pragma unroll
            for (int e=0;e<10;++e)
                h[e] = fmaxf(0.f, e1w[e][0] + sg0*e1w[e][1] + sg1*e1w[e][2] + sg2*e1w[e][3]);
            Rsum[0]+=Rl0; Rsum[1]+=Rl1; Rsum[2]+=Rl2; Rsum[3]+=Rl3;
#pragma unroll
            for (int e=0;e<10;++e){
                const float he = h[e];
                Bh[0][e]+=Rl0*he; Bh[1][e]+=Rl1*he; Bh[2][e]+=Rl2*he; Bh[3][e]+=Rl3*he;
            }
            if (first && u==0 && j==0){
#pragma unroll
                for (int e=0;e<10;++e) s_a0[grp][e]=h[e];
                s_a0[grp][10]=Rl0; s_a0[grp][11]=Rl1; s_a0[grp][12]=Rl2; s_a0[grp][13]=Rl3;
            }
        }
    };

    // 2-deep software pipeline over the 4 atom-groups (16 atoms/lane)
    float4 sA  = sp4[4*j+0];
    float4 r0A = rp[16*j+0],  r1A = rp[16*j+1],  r2A = rp[16*j+2],  r3A = rp[16*j+3];
    float4 m0A = mp[12*j+0],  m1A = mp[12*j+1],  m2A = mp[12*j+2];

    float4 sB  = sp4[4*j+1];
    float4 r0B = rp[16*j+4],  r1B = rp[16*j+5],  r2B = rp[16*j+6],  r3B = rp[16*j+7];
    float4 m0B = mp[12*j+3],  m1B = mp[12*j+4],  m2B = mp[12*j+5];

    step(sA,r0A,r1A,r2A,r3A,m0A,m1A,m2A,true);

    sA  = sp4[4*j+2];
    r0A = rp[16*j+8];  r1A = rp[16*j+9];  r2A = rp[16*j+10]; r3A = rp[16*j+11];
    m0A = mp[12*j+6];  m1A = mp[12*j+7];  m2A = mp[12*j+8];

    step(sB,r0B,r1B,r2B,r3B,m0B,m1B,m2B,false);

    sB  = sp4[4*j+3];
    r0B = rp[16*j+12]; r1B = rp[16*j+13]; r2B = rp[16*j+14]; r3B = rp[16*j+15];
    m0B = mp[12*j+9];  m1B = mp[12*j+10]; m2B = mp[12*j+11];

    step(sA,r0A,r1A,r2A,r3A,m0A,m1A,m2A,false);
    step(sB,r0B,r1B,r2B,r3B,m0B,m1B,m2B,false);

    // quad butterfly-reduce the 44 accumulators
#pragma unroll
    for (int l=0;l<4;++l) {
        float v=Rsum[l]; v+=__shfl_xor(v,1); v+=__shfl_xor(v,2); Rsum[l]=v;
#pragma unroll
        for (int e=0;e<10;++e) {
            float w=Bh[l][e]; w+=__shfl_xor(w,1); w+=__shfl_xor(w,2); Bh[l][e]=w;
        }
    }

    // lanes 2,3 (value head): subtract atom-0 rank-1 contribution
    if (j>=2) {
        const float* a0p = &s_a0[grp][0];
#pragma unroll
        for (int l=0;l<4;++l) {
            const float r0 = a0p[10+l];
            Rsum[l] -= r0;
#pragma unroll
            for (int e=0;e<10;++e) Bh[l][e] -= r0*a0p[e];
        }
    }

    // per-lane D rows: lane j -> rows [10j,10j+10), k=j&1
    const int k = j & 1;
    float Bk[4];
    {
        const float4 c0 = *(const float4*)&s_e2[k][0];
        const float4 c1 = *(const float4*)&s_e2[k][4];
        const float4 c2 = *(const float4*)&s_e2[k][8];
#pragma unroll
        for (int l=0;l<4;++l)
            Bk[l] = Rsum[l]*c0.x + Bh[l][0]*c0.y + Bh[l][1]*c0.z + Bh[l][2]*c0.w
                  + Bh[l][3]*c1.x + Bh[l][4]*c1.y + Bh[l][5]*c1.z + Bh[l][6]*c1.w
                  + Bh[l][7]*c2.x + Bh[l][8]*c2.y + Bh[l][9]*c2.z;
    }

    if (active) {
        const size_t N = (size_t)n;
        float* dst = Dws + (size_t)(10*j)*N + act;
#pragma unroll
        for (int q=0;q<10;++q) {
            const float4 c0 = *(const float4*)&s_e2[q][0];
            const float4 c1 = *(const float4*)&s_e2[q][4];
            const float4 c2 = *(const float4*)&s_e2[q][8];
            float Bq[4];
#pragma unroll
            for (int l=0;l<4;++l)
                Bq[l] = Rsum[l]*c0.x + Bh[l][0]*c0.y + Bh[l][1]*c0.z + Bh[l][2]*c0.w
                      + Bh[l][3]*c1.x + Bh[l][4]*c1.y + Bh[l][5]*c1.z + Bh[l][6]*c1.w
                      + Bh[l][7]*c2.x + Bh[l][8]*c2.y + Bh[l][9]*c2.z;
            dst[(size_t)q*N] = Bk[0]*Bq[0]+Bk[1]*Bq[1]+Bk[2]*Bq[2]+Bk[3]*Bq[3];
        }
    }
}

// ===========================================================================
// Kernel B: 1 thread = 1 action, both heads; weights in LDS (uniform broadcast).
// ===========================================================================
__global__ __launch_bounds__(256) void k_mlp(
    const float* __restrict__ Dws,
    const float* __restrict__ Wf1, const float* __restrict__ bf1,
    const float* __restrict__ Wf2, const float* __restrict__ bf2,
    const float* __restrict__ Wf3, const float* __restrict__ bf3,
    const float* __restrict__ Wv1, const float* __restrict__ bv1,
    const float* __restrict__ Wv2, const float* __restrict__ bv2,
    const float* __restrict__ Wv3, const float* __restrict__ bv3,
    float* __restrict__ logits, float* __restrict__ pmax,
    float* __restrict__ psum, float* __restrict__ pval, int n)
{
    __shared__ __align__(16) float s_f1[640], s_v1[640];
    __shared__ __align__(16) float s_f2[1024], s_v2[1024];
    __shared__ __align__(16) float s_b1[32], s_b2[32], s_f3[32];
    __shared__ __align__(16) float s_bv1[32], s_bv2[32], s_v3[32];
    __shared__ float red_l[256], red_v[256];

    const int tid = threadIdx.x;
    for (int i=tid;i<640;i+=256){ s_f1[i]=Wf1[i]; s_v1[i]=Wv1[i]; }
    for (int i=tid;i<1024;i+=256){ s_f2[i]=Wf2[i]; s_v2[i]=Wv2[i]; }
    if (tid<32){ s_b1[tid]=bf1[tid]; s_b2[tid]=bf2[tid]; s_f3[tid]=Wf3[tid];
                 s_bv1[tid]=bv1[tid]; s_bv2[tid]=bv2[tid]; s_v3[tid]=Wv3[tid]; }
    __syncthreads();

    const int i = blockIdx.x*256 + tid;
    const bool active = i < n;
    const int ic = active ? i : (n-1);
    const size_t N = (size_t)n;

    float x[20];
#pragma unroll
    for (int c=0;c<20;++c) x[c] = Dws[(size_t)c*N + ic];
    const float logit = full_head(x, s_f1, s_b1, s_f2, s_b2, s_f3) + bf3[0];

#pragma unroll
    for (int c=0;c<20;++c) x[c] = Dws[(size_t)(20+c)*N + ic];
    const float vout  = full_head(x, s_v1, s_bv1, s_v2, s_bv2, s_v3) + bv3[0];

    if (active) logits[i] = logit;
    red_l[tid] = active ? logit : -INFINITY;
    red_v[tid] = active ? vout  : 0.f;
    __syncthreads();

    if (tid < 64) {
        float m = red_l[tid];
#pragma unroll
        for (int k=1;k<4;++k) m = fmaxf(m, red_l[tid+64*k]);
#pragma unroll
        for (int k=1;k<64;k<<=1) m = fmaxf(m, __shfl_xor(m,k));
        float ssum = 0.f, vsum = 0.f;
#pragma unroll
        for (int k=0;k<4;++k) {
            ssum += expf(red_l[tid+64*k] - m);   // -inf -> 0
            vsum += red_v[tid+64*k];
        }
#pragma unroll
        for (int k=1;k<64;k<<=1){ ssum += __shfl_xor(ssum,k); vsum += __shfl_xor(vsum,k); }
        if (tid==0){ pmax[blockIdx.x]=m; psum[blockIdx.x]=ssum; pval[blockIdx.x]=vsum; }
    }
}

// ===========================================================================
// Fused fallback (R3 structure, plain 256 bound — the proven-safe config)
// ===========================================================================
__global__ __launch_bounds__(256) void k_fused(
    const float* __restrict__ Smat, const float* __restrict__ Rraw, const float* __restrict__ Mspec,
    const float* __restrict__ We1, const float* __restrict__ be1,
    const float* __restrict__ We2, const float* __restrict__ be2,
    const float* __restrict__ Wf1, const float* __restrict__ bf1,
    const float* __restrict__ Wf2, const float* __restrict__ bf2,
    const float* __restrict__ Wf3, const float* __restrict__ bf3,
    const float* __restrict__ Wv1, const float* __restrict__ bv1,
    const float* __restrict__ Wv2, const float* __restrict__ bv2,
    const float* __restrict__ Wv3, const float* __restrict__ bv3,
    float* __restrict__ logits, float* __restrict__ pmax,
    float* __restrict__ psum, float* __restrict__ pval, int n)
{
    __shared__ __align__(16) float4 s_e1[10];
    __shared__ __align__(16) float  s_e2[10][12];
    __shared__ __align__(16) float  s_f1[640], s_v1[640];
    __shared__ __align__(16) float  s_f2[1024], s_v2[1024];
    __shared__ __align__(16) float  s_b1[32], s_b2[32], s_f3[32];
    __shared__ __align__(16) float  s_bv1[32], s_bv2[32], s_v3[32];
    __shared__ __align__(16) float  s_a0[64][16];
    __shared__ float red_l[64], red_v[64];

    const int tid = threadIdx.x;
    for (int i=tid;i<640;i+=256){ s_f1[i]=Wf1[i]; s_v1[i]=Wv1[i]; }
    for (int i=tid;i<1024;i+=256){ s_f2[i]=Wf2[i]; s_v2[i]=Wv2[i]; }
    if (tid<32){ s_b1[tid]=bf1[tid]; s_b2[tid]=bf2[tid]; s_f3[tid]=Wf3[tid];
                 s_bv1[tid]=bv1[tid]; s_bv2[tid]=bv2[tid]; s_v3[tid]=Wv3[tid]; }
    if (tid<10){
        s_e1[tid] = make_float4(be1[tid], We1[tid], We1[10+tid], We1[20+tid]);
        s_e2[tid][0] = be2[tid];
        for (int e=0;e<10;++e) s_e2[tid][1+e] = We2[e*10+tid];
        s_e2[tid][11] = 0.f;
    }
    __syncthreads();

    const int j    = tid & 3;
    const int grp  = tid >> 2;
    const int act  = blockIdx.x*64 + grp;
    const bool active = act < n;
    const int actc = active ? act : (n-1);

    const float*  sp = Smat + (size_t)actc*ATOM;
    const float4* rp = (const float4*)Rraw  + (size_t)actc*ATOM;
    const float4* mp = (const float4*)Mspec + (size_t)actc*48;

    float Bh[4][10];
    float Rsum[4] = {0.f,0.f,0.f,0.f};
#pragma unroll
    for (int l=0;l<4;++l)
#pragma unroll
        for (int e=0;e<10;++e) Bh[l][e]=0.f;

#pragma unroll 1
    for (int c=0;c<4;++c) {
        const int a0 = 16*j + 4*c;
        const float4 s4 = *(const float4*)(sp + a0);
        const float4 rv0 = rp[a0+0];
        const float4 rv1 = rp[a0+1];
        const float4 rv2 = rp[a0+2];
        const float4 rv3 = rp[a0+3];
        const float4 mA = mp[12*j+3*c+0];
        const float4 mB = mp[12*j+3*c+1];
        const float4 mC = mp[12*j+3*c+2];

        const float  sv[4]  = {s4.x,s4.y,s4.z,s4.w};
        const float4 rv[4]  = {rv0,rv1,rv2,rv3};
        const float  mk[12] = {mA.x,mA.y,mA.z,mA.w,mB.x,mB.y,mB.z,mB.w,mC.x,mC.y,mC.z,mC.w};

#pragma unroll
        for (int u=0;u<4;++u) {
            const float s   = sv[u];
            const float Rl0 = s*rv[u].x, Rl1 = s*rv[u].y, Rl2 = s*rv[u].z, Rl3 = s*rv[u].w;
            const float sg0 = s*mk[3*u+0], sg1 = s*mk[3*u+1], sg2 = s*mk[3*u+2];
            float h[10];
#pragma unroll
            for (int e=0;e<10;++e) {
                const float4 w = s_e1[e];
                h[e] = fmaxf(0.f, w.x + sg0*w.y + sg1*w.z + sg2*w.w);
            }
            Rsum[0]+=Rl0; Rsum[1]+=Rl1; Rsum[2]+=Rl2; Rsum[3]+=Rl3;
#pragma unroll
            for (int e=0;e<10;++e) {
                const float he = h[e];
                Bh[0][e]+=Rl0*he; Bh[1][e]+=Rl1*he; Bh[2][e]+=Rl2*he; Bh[3][e]+=Rl3*he;
            }
            if (c==0 && u==0 && j==0) {
#pragma unroll
                for (int e=0;e<10;++e) s_a0[grp][e]=h[e];
                s_a0[grp][10]=Rl0; s_a0[grp][11]=Rl1; s_a0[grp][12]=Rl2; s_a0[grp][13]=Rl3;
            }
        }
    }

#pragma unroll
    for (int l=0;l<4;++l) {
        float v=Rsum[l]; v+=__shfl_xor(v,1); v+=__shfl_xor(v,2); Rsum[l]=v;
#pragma unroll
        for (int e=0;e<10;++e) {
            float w=Bh[l][e]; w+=__shfl_xor(w,1); w+=__shfl_xor(w,2); Bh[l][e]=w;
        }
    }

    float Df[20];
    make_D(Bh, Rsum, s_e2, Df);
    {
        const float* a0p = &s_a0[grp][0];
#pragma unroll
        for (int l=0;l<4;++l) {
            const float r0 = a0p[10+l];
            Rsum[l] -= r0;
#pragma unroll
            for (int e=0;e<10;++e) Bh[l][e] -= r0*a0p[e];
        }
    }
    float Dv[20];
    make_D(Bh, Rsum, s_e2, Dv);

    const float logit = mlp_head_quad(Df, s_f1, s_b1, s_f2, s_b2, s_f3, j) + bf3[0];
    const float vout  = mlp_head_quad(Dv, s_v1, s_bv1, s_v2, s_bv2, s_v3, j) + bv3[0];

    if (j==0) {
        red_l[grp] = active ? logit : -INFINITY;
        red_v[grp] = active ? vout  : 0.f;
        if (active) logits[act] = logit;
    }
    __syncthreads();

    if (tid < 64) {
        float m = red_l[tid];
#pragma unroll
        for (int k=1;k<64;k<<=1) m = fmaxf(m, __shfl_xor(m,k));
        float e = expf(red_l[tid] - m);
        float ssum = e, vsum = red_v[tid];
#pragma unroll
        for (int k=1;k<64;k<<=1){ ssum += __shfl_xor(ssum,k); vsum += __shfl_xor(vsum,k); }
        if (tid==0){ pmax[blockIdx.x]=m; psum[blockIdx.x]=ssum; pval[blockIdx.x]=vsum; }
    }
}

// ===========================================================================
// Kernel: merge per-block partials -> logZ, value
// ===========================================================================
__global__ __launch_bounds__(256) void k_reduce(const float* __restrict__ pmax,
                                                const float* __restrict__ psum,
                                                const float* __restrict__ pval,
                                                int nb,
                                                float* __restrict__ logZ,
                                                float* __restrict__ value_out)
{
    __shared__ float sm[256];
    const int tid = threadIdx.x;
    float m = -INFINITY;
    for (int i=tid;i<nb;i+=256) m = fmaxf(m, pmax[i]);
    sm[tid]=m; __syncthreads();
    for (int s=128;s>0;s>>=1){ if (tid<s) sm[tid]=fmaxf(sm[tid],sm[tid+s]); __syncthreads(); }
    const float M = sm[0]; __syncthreads();

    float ssum=0.f, vsum=0.f;
    for (int i=tid;i<nb;i+=256){ ssum += psum[i]*expf(pmax[i]-M); vsum += pval[i]; }
    sm[tid]=ssum; __syncthreads();
    for (int s=128;s>0;s>>=1){ if (tid<s) sm[tid]+=sm[tid+s]; __syncthreads(); }
    const float S = sm[0]; __syncthreads();

    sm[tid]=vsum; __syncthreads();
    for (int s=128;s>0;s>>=1){ if (tid<s) sm[tid]+=sm[tid+s]; __syncthreads(); }
    if (tid==0){ *logZ = M + logf(S); *value_out = sm[0]; }
}

__global__ __launch_bounds__(256) void k_apply(const float* __restrict__ logits,
                                               const float* __restrict__ logZ,
                                               float* __restrict__ out, int n)
{
    const int i = blockIdx.x*256 + threadIdx.x;
    if (i < n) out[i] = logits[i] - logZ[0];
}

extern "C" void kernel_launch(void* const* d_in, const int* in_sizes, int n_in,
                              void* d_out, int out_size, void* d_ws, size_t ws_size,
                              hipStream_t stream)
{
    const float* Smat  = (const float*)d_in[0];
    const float* Rraw  = (const float*)d_in[1];
    const float* Mspec = (const float*)d_in[2];
    const float* We1 = (const float*)d_in[3];  const float* be1 = (const float*)d_in[4];
    const float* We2 = (const float*)d_in[5];  const float* be2 = (const float*)d_in[6];
    const float* Wf1 = (const float*)d_in[7];  const float* bf1 = (const float*)d_in[8];
    const float* Wf2 = (const float*)d_in[9];  const float* bf2 = (const float*)d_in[10];
    const float* Wf3 = (const float*)d_in[11]; const float* bf3 = (const float*)d_in[12];
    const float* Wv1 = (const float*)d_in[13]; const float* bv1 = (const float*)d_in[14];
    const float* Wv2 = (const float*)d_in[15]; const float* bv2 = (const float*)d_in[16];
    const float* Wv3 = (const float*)d_in[17]; const float* bv3 = (const float*)d_in[18];

    const int n   = in_sizes[0] / ATOM;
    const int nb1 = (n + 63) / 64;            // k_desc / k_fused blocks
    const int nb2 = (n + 255) / 256;          // k_mlp blocks

    float* out = (float*)d_out;               // [n] policy, [1] value
    const size_t need = ((size_t)40*n + n + 3*(size_t)nb2 + 16) * sizeof(float);

    if (ws_size >= need) {
        float* ws     = (float*)d_ws;
        float* Dws    = ws;                    // [40*n]
        float* logits = Dws + (size_t)40*n;    // [n]
        float* pmax   = logits + n;            // [nb2]
        float* psum   = pmax + nb2;            // [nb2]
        float* pval   = psum + nb2;            // [nb2]
        float* logZ   = pval + nb2;            // [1]

        k_desc<<<nb1, 256, 0, stream>>>(Smat, Rraw, Mspec, We1, be1, We2, be2, Dws, n);
        k_mlp<<<nb2, 256, 0, stream>>>(Dws,
                                       Wf1, bf1, Wf2, bf2, Wf3, bf3,
                                       Wv1, bv1, Wv2, bv2, Wv3, bv3,
                                       logits, pmax, psum, pval, n);
        k_reduce<<<1, 256, 0, stream>>>(pmax, psum, pval, nb2, logZ, out + n);
        k_apply<<<(n + 255)/256, 256, 0, stream>>>(logits, logZ, out, n);
    } else {
        float* ws     = (float*)d_ws;
        float* logits = ws;                    // [n]
        float* pmax   = ws + n;                // [nb1]
        float* psum   = pmax + nb1;            // [nb1]
        float* pval   = psum + nb1;            // [nb1]
        float* logZ   = pval + nb1;            // [1]

        k_fused<<<nb1, 256, 0, stream>>>(Smat, Rraw, Mspec,
                                         We1, be1, We2, be2,
                                         Wf1, bf1, Wf2, bf2, Wf3, bf3,
                                         Wv1, bv1, Wv2, bv2, Wv3, bv3,
                                         logits, pmax, psum, pval, n);
        k_reduce<<<1, 256, 0, stream>>>(pmax, psum, pval, nb1, logZ, out + n);
        k_apply<<<(n + 255)/256, 256, 0, stream>>>(logits, logZ, out, n);
    }
}

// Round 7
// 99.559 us; speedup vs baseline: 4.3632x; 1.1833x over previous
//
#include <hip/hip_runtime.h>
#include <math.h>

#define ATOM 64

// ===========================================================================
// Shared device helpers
// ===========================================================================

// D[k][q] = sum_l B[l][k] * B[l][q], with B[l][q] = Rsum[l]*be2[q] + sum_e Bh[l][e]*We2[e][q]
// e2 column layout: e2[q] = { be2[q], We2[0][q], ..., We2[9][q], pad }
__device__ __forceinline__ void make_D(const float (&Bh)[4][10], const float (&Rsum)[4],
                                       const float (*e2)[12], float (&D)[20])
{
    float Bk[2][4];
#pragma unroll
    for (int k=0;k<2;++k) {
        const float4 c0 = *(const float4*)&e2[k][0];
        const float4 c1 = *(const float4*)&e2[k][4];
        const float4 c2 = *(const float4*)&e2[k][8];
#pragma unroll
        for (int l=0;l<4;++l) {
            Bk[k][l] = Rsum[l]*c0.x + Bh[l][0]*c0.y + Bh[l][1]*c0.z + Bh[l][2]*c0.w
                     + Bh[l][3]*c1.x + Bh[l][4]*c1.y + Bh[l][5]*c1.z + Bh[l][6]*c1.w
                     + Bh[l][7]*c2.x + Bh[l][8]*c2.y + Bh[l][9]*c2.z;
        }
    }
#pragma unroll
    for (int q=0;q<10;++q) {
        const float4 c0 = *(const float4*)&e2[q][0];
        const float4 c1 = *(const float4*)&e2[q][4];
        const float4 c2 = *(const float4*)&e2[q][8];
        float Bq[4];
#pragma unroll
        for (int l=0;l<4;++l) {
            Bq[l] = Rsum[l]*c0.x + Bh[l][0]*c0.y + Bh[l][1]*c0.z + Bh[l][2]*c0.w
                  + Bh[l][3]*c1.x + Bh[l][4]*c1.y + Bh[l][5]*c1.z + Bh[l][6]*c1.w
                  + Bh[l][7]*c2.x + Bh[l][8]*c2.y + Bh[l][9]*c2.z;
        }
        D[q]    = Bk[0][0]*Bq[0]+Bk[0][1]*Bq[1]+Bk[0][2]*Bq[2]+Bk[0][3]*Bq[3];
        D[10+q] = Bk[1][0]*Bq[0]+Bk[1][1]*Bq[1]+Bk[1][2]*Bq[2]+Bk[1][3]*Bq[3];
    }
}

// quad-cooperative MLP head (used by fused fallback only)
__device__ __forceinline__ float mlp_head_quad(const float* __restrict__ x,
                                          const float* __restrict__ w1, const float* __restrict__ b1,
                                          const float* __restrict__ w2, const float* __restrict__ b2,
                                          const float* __restrict__ w3, int j)
{
    float h1[8];
    {
        float4 ba = *(const float4*)(b1 + 8*j);
        float4 bb = *(const float4*)(b1 + 8*j + 4);
        h1[0]=ba.x; h1[1]=ba.y; h1[2]=ba.z; h1[3]=ba.w;
        h1[4]=bb.x; h1[5]=bb.y; h1[6]=bb.z; h1[7]=bb.w;
    }
#pragma unroll
    for (int d=0; d<20; ++d) {
        float4 w0 = *(const float4*)(w1 + d*32 + 8*j);
        float4 w4 = *(const float4*)(w1 + d*32 + 8*j + 4);
        float xv = x[d];
        h1[0] += xv*w0.x; h1[1] += xv*w0.y; h1[2] += xv*w0.z; h1[3] += xv*w0.w;
        h1[4] += xv*w4.x; h1[5] += xv*w4.y; h1[6] += xv*w4.z; h1[7] += xv*w4.w;
    }
#pragma unroll
    for (int o=0;o<8;++o) h1[o] = fmaxf(h1[o], 0.f);

    float s = 0.f;
#pragma unroll
    for (int half=0; half<2; ++half) {
        float p[16];
#pragma unroll
        for (int q=0;q<16;++q) p[q] = 0.f;
#pragma unroll
        for (int o=0;o<8;++o) {
            const float* row = w2 + (8*j + o)*32 + 16*half;
            float hv = h1[o];
#pragma unroll
            for (int q=0;q<4;++q) {
                float4 w = *(const float4*)(row + 4*q);
                p[4*q+0] += hv*w.x; p[4*q+1] += hv*w.y;
                p[4*q+2] += hv*w.z; p[4*q+3] += hv*w.w;
            }
        }
#pragma unroll
        for (int q=0;q<16;++q) { p[q] += __shfl_xor(p[q],1); p[q] += __shfl_xor(p[q],2); }
#pragma unroll
        for (int q=0;q<4;++q) {
            float4 bq = *(const float4*)(b2 + 16*half + 4*q);
            float4 wq = *(const float4*)(w3 + 16*half + 4*q);
            s += fmaxf(p[4*q+0]+bq.x, 0.f)*wq.x;
            s += fmaxf(p[4*q+1]+bq.y, 0.f)*wq.y;
            s += fmaxf(p[4*q+2]+bq.z, 0.f)*wq.z;
            s += fmaxf(p[4*q+3]+bq.w, 0.f)*wq.w;
        }
    }
    return s;
}

// full per-thread MLP head: x[20] -> 32 -> 32 -> 1 (bias3 added by caller)
__device__ __forceinline__ float full_head(const float (&x)[20],
                                           const float* __restrict__ w1, const float* __restrict__ b1,
                                           const float* __restrict__ w2, const float* __restrict__ b2,
                                           const float* __restrict__ w3)
{
    float h1[32];
#pragma unroll
    for (int q=0;q<8;++q) {
        float4 b = *(const float4*)(b1 + 4*q);
        h1[4*q+0]=b.x; h1[4*q+1]=b.y; h1[4*q+2]=b.z; h1[4*q+3]=b.w;
    }
#pragma unroll
    for (int d=0; d<20; ++d) {
        const float xv = x[d];
        const float* row = w1 + d*32;
#pragma unroll
        for (int q=0;q<8;++q) {
            float4 w = *(const float4*)(row + 4*q);
            h1[4*q+0] += xv*w.x; h1[4*q+1] += xv*w.y;
            h1[4*q+2] += xv*w.z; h1[4*q+3] += xv*w.w;
        }
    }
    float p[32];
#pragma unroll
    for (int q=0;q<8;++q) {
        float4 b = *(const float4*)(b2 + 4*q);
        p[4*q+0]=b.x; p[4*q+1]=b.y; p[4*q+2]=b.z; p[4*q+3]=b.w;
    }
#pragma unroll
    for (int o=0;o<32;++o) {
        const float hv = fmaxf(h1[o], 0.f);
        const float* row = w2 + o*32;
#pragma unroll
        for (int q=0;q<8;++q) {
            float4 w = *(const float4*)(row + 4*q);
            p[4*q+0] += hv*w.x; p[4*q+1] += hv*w.y;
            p[4*q+2] += hv*w.z; p[4*q+3] += hv*w.w;
        }
    }
    float s = 0.f;
#pragma unroll
    for (int q=0;q<8;++q) {
        float4 wq = *(const float4*)(w3 + 4*q);
        s += fmaxf(p[4*q+0], 0.f)*wq.x;
        s += fmaxf(p[4*q+1], 0.f)*wq.y;
        s += fmaxf(p[4*q+2], 0.f)*wq.z;
        s += fmaxf(p[4*q+3], 0.f)*wq.w;
    }
    return s;
}

// ===========================================================================
// Kernel A (R7): descriptor only. 4 lanes/action, INTERLEAVED atom ownership:
// lane j owns atoms {4u+j}. All R loads fully coalesced (quad reads 64B
// contiguous per instruction). 2 actions per quad, cross-action prefetch.
// ===========================================================================
struct Stage {
    float4 r0,r1,r2,r3;     // R float4 of atoms 16c+{0,4,8,12}+j
    float  s0,s1,s2,s3;     // Smat of same atoms
    float  m[12];           // mask triplets of same atoms
};

__device__ __forceinline__ void load_stage(Stage& st, const float4* __restrict__ rp_l,
                                           const float* __restrict__ sp_l,
                                           const float* __restrict__ mp_l, int c)
{
    st.r0 = rp_l[16*c+0]; st.r1 = rp_l[16*c+4]; st.r2 = rp_l[16*c+8]; st.r3 = rp_l[16*c+12];
    st.s0 = sp_l[16*c+0]; st.s1 = sp_l[16*c+4]; st.s2 = sp_l[16*c+8]; st.s3 = sp_l[16*c+12];
#pragma unroll
    for (int t=0;t<4;++t){
        st.m[3*t+0] = mp_l[48*c+12*t+0];
        st.m[3*t+1] = mp_l[48*c+12*t+1];
        st.m[3*t+2] = mp_l[48*c+12*t+2];
    }
}

__device__ __forceinline__ void step_stage(const Stage& st, float (&Bh)[4][10], float (&Rsum)[4],
                                           const float (&e1w)[10][4], float* a0slot,
                                           bool first, int j)
{
    const float  sv[4] = {st.s0, st.s1, st.s2, st.s3};
    const float4 rv[4] = {st.r0, st.r1, st.r2, st.r3};
#pragma unroll
    for (int t=0;t<4;++t){
        const float s   = sv[t];
        const float Rl0 = s*rv[t].x, Rl1 = s*rv[t].y, Rl2 = s*rv[t].z, Rl3 = s*rv[t].w;
        const float sg0 = s*st.m[3*t+0], sg1 = s*st.m[3*t+1], sg2 = s*st.m[3*t+2];
        float h[10];
#pragma unroll
        for (int e=0;e<10;++e)
            h[e] = fmaxf(0.f, e1w[e][0] + sg0*e1w[e][1] + sg1*e1w[e][2] + sg2*e1w[e][3]);
        Rsum[0]+=Rl0; Rsum[1]+=Rl1; Rsum[2]+=Rl2; Rsum[3]+=Rl3;
#pragma unroll
        for (int e=0;e<10;++e){
            const float he = h[e];
            Bh[0][e]+=Rl0*he; Bh[1][e]+=Rl1*he; Bh[2][e]+=Rl2*he; Bh[3][e]+=Rl3*he;
        }
        if (first && t==0 && j==0){     // atom 0 = (c=0,t=0,j=0)
#pragma unroll
            for (int e=0;e<10;++e) a0slot[e]=h[e];
            a0slot[10]=Rl0; a0slot[11]=Rl1; a0slot[12]=Rl2; a0slot[13]=Rl3;
        }
    }
}

// reduce + value-head fixup + per-lane D rows + store
__device__ __forceinline__ void epilogue(float (&Bh)[4][10], float (&Rsum)[4],
                                         const float (*e2)[12], const float* a0slot,
                                         float* __restrict__ Dws, int act, bool active,
                                         int n, int j)
{
#pragma unroll
    for (int l=0;l<4;++l) {
        float v=Rsum[l]; v+=__shfl_xor(v,1); v+=__shfl_xor(v,2); Rsum[l]=v;
#pragma unroll
        for (int e=0;e<10;++e) {
            float w=Bh[l][e]; w+=__shfl_xor(w,1); w+=__shfl_xor(w,2); Bh[l][e]=w;
        }
    }
    if (j>=2) {   // value head excludes atom 0
#pragma unroll
        for (int l=0;l<4;++l) {
            const float r0 = a0slot[10+l];
            Rsum[l] -= r0;
#pragma unroll
            for (int e=0;e<10;++e) Bh[l][e] -= r0*a0slot[e];
        }
    }
    const int k = j & 1;
    float Bk[4];
    {
        const float4 c0 = *(const float4*)&e2[k][0];
        const float4 c1 = *(const float4*)&e2[k][4];
        const float4 c2 = *(const float4*)&e2[k][8];
#pragma unroll
        for (int l=0;l<4;++l)
            Bk[l] = Rsum[l]*c0.x + Bh[l][0]*c0.y + Bh[l][1]*c0.z + Bh[l][2]*c0.w
                  + Bh[l][3]*c1.x + Bh[l][4]*c1.y + Bh[l][5]*c1.z + Bh[l][6]*c1.w
                  + Bh[l][7]*c2.x + Bh[l][8]*c2.y + Bh[l][9]*c2.z;
    }
    if (active) {
        const size_t N = (size_t)n;
        float* dst = Dws + (size_t)(10*j)*N + act;
#pragma unroll
        for (int q=0;q<10;++q) {
            const float4 c0 = *(const float4*)&e2[q][0];
            const float4 c1 = *(const float4*)&e2[q][4];
            const float4 c2 = *(const float4*)&e2[q][8];
            float Bq[4];
#pragma unroll
            for (int l=0;l<4;++l)
                Bq[l] = Rsum[l]*c0.x + Bh[l][0]*c0.y + Bh[l][1]*c0.z + Bh[l][2]*c0.w
                      + Bh[l][3]*c1.x + Bh[l][4]*c1.y + Bh[l][5]*c1.z + Bh[l][6]*c1.w
                      + Bh[l][7]*c2.x + Bh[l][8]*c2.y + Bh[l][9]*c2.z;
            dst[(size_t)q*N] = Bk[0]*Bq[0]+Bk[1]*Bq[1]+Bk[2]*Bq[2]+Bk[3]*Bq[3];
        }
    }
}

__global__ __launch_bounds__(256) void k_desc(
    const float* __restrict__ Smat, const float* __restrict__ Rraw, const float* __restrict__ Mspec,
    const float* __restrict__ We1, const float* __restrict__ be1,
    const float* __restrict__ We2, const float* __restrict__ be2,
    float* __restrict__ Dws, int n)
{
    __shared__ __align__(16) float s_e2[10][12]; // col q: {b_e2[q], We2[0..9][q], pad}
    __shared__ __align__(16) float s_a0[64][16]; // per-quad atom-0 {h0[10], R0[4]}

    const int tid = threadIdx.x;
    if (tid<10){
        s_e2[tid][0] = be2[tid];
        for (int e=0;e<10;++e) s_e2[tid][1+e] = We2[e*10+tid];
        s_e2[tid][11] = 0.f;
    }
    __syncthreads();

    float e1w[10][4];
#pragma unroll
    for (int e=0;e<10;++e){
        e1w[e][0]=be1[e]; e1w[e][1]=We1[e]; e1w[e][2]=We1[10+e]; e1w[e][3]=We1[20+e];
    }

    const int j    = tid & 3;
    const int grp  = tid >> 2;
    float* a0slot  = &s_a0[grp][0];

    const int act1 = blockIdx.x*128 + grp;        // first action of this quad
    const int act2 = act1 + 64;                   // second action
    const bool av1 = act1 < n;
    const bool av2 = act2 < n;
    const int a1c  = av1 ? act1 : (n-1);
    const int a2c  = av2 ? act2 : (n-1);

    // lane-adjusted base pointers (interleaved ownership: atom = 4u + j)
    const float4* rp1 = (const float4*)Rraw + (size_t)a1c*ATOM + j;
    const float*  sp1 = Smat  + (size_t)a1c*ATOM + j;
    const float*  mp1 = Mspec + (size_t)a1c*(ATOM*3) + 3*j;
    const float4* rp2 = (const float4*)Rraw + (size_t)a2c*ATOM + j;
    const float*  sp2 = Smat  + (size_t)a2c*ATOM + j;
    const float*  mp2 = Mspec + (size_t)a2c*(ATOM*3) + 3*j;

    float Bh[4][10];
    float Rsum[4] = {0.f,0.f,0.f,0.f};
#pragma unroll
    for (int l=0;l<4;++l)
#pragma unroll
        for (int e=0;e<10;++e) Bh[l][e]=0.f;

    Stage A, B;
    // ---- action 1: 4 super-steps, 2-deep pipeline ----
    load_stage(A, rp1, sp1, mp1, 0);
    load_stage(B, rp1, sp1, mp1, 1);

    step_stage(A, Bh, Rsum, e1w, a0slot, true,  j);
    load_stage(A, rp1, sp1, mp1, 2);
    step_stage(B, Bh, Rsum, e1w, a0slot, false, j);
    load_stage(B, rp1, sp1, mp1, 3);
    step_stage(A, Bh, Rsum, e1w, a0slot, false, j);
    load_stage(A, rp2, sp2, mp2, 0);              // prefetch action 2, step 0
    step_stage(B, Bh, Rsum, e1w, a0slot, false, j);
    load_stage(B, rp2, sp2, mp2, 1);              // prefetch action 2, step 1

    epilogue(Bh, Rsum, s_e2, a0slot, Dws, act1, av1, n, j);   // covers prefetch latency

    // ---- action 2 ----
#pragma unroll
    for (int l=0;l<4;++l){ Rsum[l]=0.f;
#pragma unroll
        for (int e=0;e<10;++e) Bh[l][e]=0.f; }

    step_stage(A, Bh, Rsum, e1w, a0slot, true,  j);
    load_stage(A, rp2, sp2, mp2, 2);
    step_stage(B, Bh, Rsum, e1w, a0slot, false, j);
    load_stage(B, rp2, sp2, mp2, 3);
    step_stage(A, Bh, Rsum, e1w, a0slot, false, j);
    step_stage(B, Bh, Rsum, e1w, a0slot, false, j);

    epilogue(Bh, Rsum, s_e2, a0slot, Dws, act2, av2, n, j);
}

// ===========================================================================
// Kernel B: 1 thread = 1 action, both heads; weights in LDS (uniform broadcast).
// ===========================================================================
__global__ __launch_bounds__(256) void k_mlp(
    const float* __restrict__ Dws,
    const float* __restrict__ Wf1, const float* __restrict__ bf1,
    const float* __restrict__ Wf2, const float* __restrict__ bf2,
    const float* __restrict__ Wf3, const float* __restrict__ bf3,
    const float* __restrict__ Wv1, const float* __restrict__ bv1,
    const float* __restrict__ Wv2, const float* __restrict__ bv2,
    const float* __restrict__ Wv3, const float* __restrict__ bv3,
    float* __restrict__ logits, float* __restrict__ pmax,
    float* __restrict__ psum, float* __restrict__ pval, int n)
{
    __shared__ __align__(16) float s_f1[640], s_v1[640];
    __shared__ __align__(16) float s_f2[1024], s_v2[1024];
    __shared__ __align__(16) float s_b1[32], s_b2[32], s_f3[32];
    __shared__ __align__(16) float s_bv1[32], s_bv2[32], s_v3[32];
    __shared__ float red_l[256], red_v[256];

    const int tid = threadIdx.x;
    for (int i=tid;i<640;i+=256){ s_f1[i]=Wf1[i]; s_v1[i]=Wv1[i]; }
    for (int i=tid;i<1024;i+=256){ s_f2[i]=Wf2[i]; s_v2[i]=Wv2[i]; }
    if (tid<32){ s_b1[tid]=bf1[tid]; s_b2[tid]=bf2[tid]; s_f3[tid]=Wf3[tid];
                 s_bv1[tid]=bv1[tid]; s_bv2[tid]=bv2[tid]; s_v3[tid]=Wv3[tid]; }
    __syncthreads();

    const int i = blockIdx.x*256 + tid;
    const bool active = i < n;
    const int ic = active ? i : (n-1);
    const size_t N = (size_t)n;

    float x[20];
#pragma unroll
    for (int c=0;c<20;++c) x[c] = Dws[(size_t)c*N + ic];
    const float logit = full_head(x, s_f1, s_b1, s_f2, s_b2, s_f3) + bf3[0];

#pragma unroll
    for (int c=0;c<20;++c) x[c] = Dws[(size_t)(20+c)*N + ic];
    const float vout  = full_head(x, s_v1, s_bv1, s_v2, s_bv2, s_v3) + bv3[0];

    if (active) logits[i] = logit;
    red_l[tid] = active ? logit : -INFINITY;
    red_v[tid] = active ? vout  : 0.f;
    __syncthreads();

    if (tid < 64) {
        float m = red_l[tid];
#pragma unroll
        for (int k=1;k<4;++k) m = fmaxf(m, red_l[tid+64*k]);
#pragma unroll
        for (int k=1;k<64;k<<=1) m = fmaxf(m, __shfl_xor(m,k));
        float ssum = 0.f, vsum = 0.f;
#pragma unroll
        for (int k=0;k<4;++k) {
            ssum += expf(red_l[tid+64*k] - m);   // -inf -> 0
            vsum += red_v[tid+64*k];
        }
#pragma unroll
        for (int k=1;k<64;k<<=1){ ssum += __shfl_xor(ssum,k); vsum += __shfl_xor(vsum,k); }
        if (tid==0){ pmax[blockIdx.x]=m; psum[blockIdx.x]=ssum; pval[blockIdx.x]=vsum; }
    }
}

// ===========================================================================
// Fused fallback (R3 structure, plain 256 bound — the proven-safe config)
// ===========================================================================
__global__ __launch_bounds__(256) void k_fused(
    const float* __restrict__ Smat, const float* __restrict__ Rraw, const float* __restrict__ Mspec,
    const float* __restrict__ We1, const float* __restrict__ be1,
    const float* __restrict__ We2, const float* __restrict__ be2,
    const float* __restrict__ Wf1, const float* __restrict__ bf1,
    const float* __restrict__ Wf2, const float* __restrict__ bf2,
    const float* __restrict__ Wf3, const float* __restrict__ bf3,
    const float* __restrict__ Wv1, const float* __restrict__ bv1,
    const float* __restrict__ Wv2, const float* __restrict__ bv2,
    const float* __restrict__ Wv3, const float* __restrict__ bv3,
    float* __restrict__ logits, float* __restrict__ pmax,
    float* __restrict__ psum, float* __restrict__ pval, int n)
{
    __shared__ __align__(16) float4 s_e1[10];
    __shared__ __align__(16) float  s_e2[10][12];
    __shared__ __align__(16) float  s_f1[640], s_v1[640];
    __shared__ __align__(16) float  s_f2[1024], s_v2[1024];
    __shared__ __align__(16) float  s_b1[32], s_b2[32], s_f3[32];
    __shared__ __align__(16) float  s_bv1[32], s_bv2[32], s_v3[32];
    __shared__ __align__(16) float  s_a0[64][16];
    __shared__ float red_l[64], red_v[64];

    const int tid = threadIdx.x;
    for (int i=tid;i<640;i+=256){ s_f1[i]=Wf1[i]; s_v1[i]=Wv1[i]; }
    for (int i=tid;i<1024;i+=256){ s_f2[i]=Wf2[i]; s_v2[i]=Wv2[i]; }
    if (tid<32){ s_b1[tid]=bf1[tid]; s_b2[tid]=bf2[tid]; s_f3[tid]=Wf3[tid];
                 s_bv1[tid]=bv1[tid]; s_bv2[tid]=bv2[tid]; s_v3[tid]=Wv3[tid]; }
    if (tid<10){
        s_e1[tid] = make_float4(be1[tid], We1[tid], We1[10+tid], We1[20+tid]);
        s_e2[tid][0] = be2[tid];
        for (int e=0;e<10;++e) s_e2[tid][1+e] = We2[e*10+tid];
        s_e2[tid][11] = 0.f;
    }
    __syncthreads();

    const int j    = tid & 3;
    const int grp  = tid >> 2;
    const int act  = blockIdx.x*64 + grp;
    const bool active = act < n;
    const int actc = active ? act : (n-1);

    const float*  sp = Smat + (size_t)actc*ATOM;
    const float4* rp = (const float4*)Rraw  + (size_t)actc*ATOM;
    const float4* mp = (const float4*)Mspec + (size_t)actc*48;

    float Bh[4][10];
    float Rsum[4] = {0.f,0.f,0.f,0.f};
#pragma unroll
    for (int l=0;l<4;++l)
#pragma unroll
        for (int e=0;e<10;++e) Bh[l][e]=0.f;

#pragma unroll 1
    for (int c=0;c<4;++c) {
        const int a0 = 16*j + 4*c;
        const float4 s4 = *(const float4*)(sp + a0);
        const float4 rv0 = rp[a0+0];
        const float4 rv1 = rp[a0+1];
        const float4 rv2 = rp[a0+2];
        const float4 rv3 = rp[a0+3];
        const float4 mA = mp[12*j+3*c+0];
        const float4 mB = mp[12*j+3*c+1];
        const float4 mC = mp[12*j+3*c+2];

        const float  sv[4]  = {s4.x,s4.y,s4.z,s4.w};
        const float4 rv[4]  = {rv0,rv1,rv2,rv3};
        const float  mk[12] = {mA.x,mA.y,mA.z,mA.w,mB.x,mB.y,mB.z,mB.w,mC.x,mC.y,mC.z,mC.w};

#pragma unroll
        for (int u=0;u<4;++u) {
            const float s   = sv[u];
            const float Rl0 = s*rv[u].x, Rl1 = s*rv[u].y, Rl2 = s*rv[u].z, Rl3 = s*rv[u].w;
            const float sg0 = s*mk[3*u+0], sg1 = s*mk[3*u+1], sg2 = s*mk[3*u+2];
            float h[10];
#pragma unroll
            for (int e=0;e<10;++e) {
                const float4 w = s_e1[e];
                h[e] = fmaxf(0.f, w.x + sg0*w.y + sg1*w.z + sg2*w.w);
            }
            Rsum[0]+=Rl0; Rsum[1]+=Rl1; Rsum[2]+=Rl2; Rsum[3]+=Rl3;
#pragma unroll
            for (int e=0;e<10;++e) {
                const float he = h[e];
                Bh[0][e]+=Rl0*he; Bh[1][e]+=Rl1*he; Bh[2][e]+=Rl2*he; Bh[3][e]+=Rl3*he;
            }
            if (c==0 && u==0 && j==0) {
#pragma unroll
                for (int e=0;e<10;++e) s_a0[grp][e]=h[e];
                s_a0[grp][10]=Rl0; s_a0[grp][11]=Rl1; s_a0[grp][12]=Rl2; s_a0[grp][13]=Rl3;
            }
        }
    }

#pragma unroll
    for (int l=0;l<4;++l) {
        float v=Rsum[l]; v+=__shfl_xor(v,1); v+=__shfl_xor(v,2); Rsum[l]=v;
#pragma unroll
        for (int e=0;e<10;++e) {
            float w=Bh[l][e]; w+=__shfl_xor(w,1); w+=__shfl_xor(w,2); Bh[l][e]=w;
        }
    }

    float Df[20];
    make_D(Bh, Rsum, s_e2, Df);
    {
        const float* a0p = &s_a0[grp][0];
#pragma unroll
        for (int l=0;l<4;++l) {
            const float r0 = a0p[10+l];
            Rsum[l] -= r0;
#pragma unroll
            for (int e=0;e<10;++e) Bh[l][e] -= r0*a0p[e];
        }
    }
    float Dv[20];
    make_D(Bh, Rsum, s_e2, Dv);

    const float logit = mlp_head_quad(Df, s_f1, s_b1, s_f2, s_b2, s_f3, j) + bf3[0];
    const float vout  = mlp_head_quad(Dv, s_v1, s_bv1, s_v2, s_bv2, s_v3, j) + bv3[0];

    if (j==0) {
        red_l[grp] = active ? logit : -INFINITY;
        red_v[grp] = active ? vout  : 0.f;
        if (active) logits[act] = logit;
    }
    __syncthreads();

    if (tid < 64) {
        float m = red_l[tid];
#pragma unroll
        for (int k=1;k<64;k<<=1) m = fmaxf(m, __shfl_xor(m,k));
        float e = expf(red_l[tid] - m);
        float ssum = e, vsum = red_v[tid];
#pragma unroll
        for (int k=1;k<64;k<<=1){ ssum += __shfl_xor(ssum,k); vsum += __shfl_xor(vsum,k); }
        if (tid==0){ pmax[blockIdx.x]=m; psum[blockIdx.x]=ssum; pval[blockIdx.x]=vsum; }
    }
}

// ===========================================================================
// Kernel: merge per-block partials -> logZ, value
// ===========================================================================
__global__ __launch_bounds__(256) void k_reduce(const float* __restrict__ pmax,
                                                const float* __restrict__ psum,
                                                const float* __restrict__ pval,
                                                int nb,
                                                float* __restrict__ logZ,
                                                float* __restrict__ value_out)
{
    __shared__ float sm[256];
    const int tid = threadIdx.x;
    float m = -INFINITY;
    for (int i=tid;i<nb;i+=256) m = fmaxf(m, pmax[i]);
    sm[tid]=m; __syncthreads();
    for (int s=128;s>0;s>>=1){ if (tid<s) sm[tid]=fmaxf(sm[tid],sm[tid+s]); __syncthreads(); }
    const float M = sm[0]; __syncthreads();

    float ssum=0.f, vsum=0.f;
    for (int i=tid;i<nb;i+=256){ ssum += psum[i]*expf(pmax[i]-M); vsum += pval[i]; }
    sm[tid]=ssum; __syncthreads();
    for (int s=128;s>0;s>>=1){ if (tid<s) sm[tid]+=sm[tid+s]; __syncthreads(); }
    const float S = sm[0]; __syncthreads();

    sm[tid]=vsum; __syncthreads();
    for (int s=128;s>0;s>>=1){ if (tid<s) sm[tid]+=sm[tid+s]; __syncthreads(); }
    if (tid==0){ *logZ = M + logf(S); *value_out = sm[0]; }
}

__global__ __launch_bounds__(256) void k_apply(const float* __restrict__ logits,
                                               const float* __restrict__ logZ,
                                               float* __restrict__ out, int n)
{
    const int i = blockIdx.x*256 + threadIdx.x;
    if (i < n) out[i] = logits[i] - logZ[0];
}

extern "C" void kernel_launch(void* const* d_in, const int* in_sizes, int n_in,
                              void* d_out, int out_size, void* d_ws, size_t ws_size,
                              hipStream_t stream)
{
    const float* Smat  = (const float*)d_in[0];
    const float* Rraw  = (const float*)d_in[1];
    const float* Mspec = (const float*)d_in[2];
    const float* We1 = (const float*)d_in[3];  const float* be1 = (const float*)d_in[4];
    const float* We2 = (const float*)d_in[5];  const float* be2 = (const float*)d_in[6];
    const float* Wf1 = (const float*)d_in[7];  const float* bf1 = (const float*)d_in[8];
    const float* Wf2 = (const float*)d_in[9];  const float* bf2 = (const float*)d_in[10];
    const float* Wf3 = (const float*)d_in[11]; const float* bf3 = (const float*)d_in[12];
    const float* Wv1 = (const float*)d_in[13]; const float* bv1 = (const float*)d_in[14];
    const float* Wv2 = (const float*)d_in[15]; const float* bv2 = (const float*)d_in[16];
    const float* Wv3 = (const float*)d_in[17]; const float* bv3 = (const float*)d_in[18];

    const int n   = in_sizes[0] / ATOM;
    const int nbD = (n + 127) / 128;          // k_desc blocks (128 actions each)
    const int nb1 = (n + 63) / 64;            // k_fused blocks
    const int nb2 = (n + 255) / 256;          // k_mlp blocks

    float* out = (float*)d_out;               // [n] policy, [1] value
    const size_t need = ((size_t)40*n + n + 3*(size_t)nb2 + 16) * sizeof(float);

    if (ws_size >= need) {
        float* ws     = (float*)d_ws;
        float* Dws    = ws;                    // [40*n]
        float* logits = Dws + (size_t)40*n;    // [n]
        float* pmax   = logits + n;            // [nb2]
        float* psum   = pmax + nb2;            // [nb2]
        float* pval   = psum + nb2;            // [nb2]
        float* logZ   = pval + nb2;            // [1]

        k_desc<<<nbD, 256, 0, stream>>>(Smat, Rraw, Mspec, We1, be1, We2, be2, Dws, n);
        k_mlp<<<nb2, 256, 0, stream>>>(Dws,
                                       Wf1, bf1, Wf2, bf2, Wf3, bf3,
                                       Wv1, bv1, Wv2, bv2, Wv3, bv3,
                                       logits, pmax, psum, pval, n);
        k_reduce<<<1, 256, 0, stream>>>(pmax, psum, pval, nb2, logZ, out + n);
        k_apply<<<(n + 255)/256, 256, 0, stream>>>(logits, logZ, out, n);
    } else {
        float* ws     = (float*)d_ws;
        float* logits = ws;                    // [n]
        float* pmax   = ws + n;                // [nb1]
        float* psum   = pmax + nb1;            // [nb1]
        float* pval   = psum + nb1;            // [nb1]
        float* logZ   = pval + nb1;            // [1]

        k_fused<<<nb1, 256, 0, stream>>>(Smat, Rraw, Mspec,
                                         We1, be1, We2, be2,
                                         Wf1, bf1, Wf2, bf2, Wf3, bf3,
                                         Wv1, bv1, Wv2, bv2, Wv3, bv3,
                                         logits, pmax, psum, pval, n);
        k_reduce<<<1, 256, 0, stream>>>(pmax, psum, pval, nb1, logZ, out + n);
        k_apply<<<(n + 255)/256, 256, 0, stream>>>(logits, logZ, out, n);
    }
}